// Round 9
// baseline (275.358 us; speedup 1.0000x reference)
//
#include <hip/hip_runtime.h>
#include <math.h>

// Problem constants
#define NB   2
#define SEQ  2048
#define CH   768
#define NH   12
#define HD   64
#define F3   2304
#define LSMAX 4.605170185988092f
#define LOG2E 1.4426950408889634f

typedef _Float16 f16;
typedef __attribute__((ext_vector_type(8))) _Float16 f16x8;
typedef __attribute__((ext_vector_type(4))) _Float16 f16x4;
typedef __attribute__((ext_vector_type(2))) _Float16 f16x2;
typedef __attribute__((ext_vector_type(4))) float f32x4;

// f16 workspace layout (units: f16 elements)
#define QSZ   3145728                 // per Q/K/V tensor
#define OATT  (3 * QSZ)               // attn out [N,L,C] f16 (3145728)
#define XHOFF 12582912                // x -> f16 (3145728)
#define W1OFF 15728640                // in_proj_w -> f16 (1769472)
#define W2OFF 17498112                // out_proj_w -> f16 (589824)
#define FLAGO 18087936                // int flag: mask nonzero

// LDS pitches
#define VP   136   // attn Vt tile (128 keys): 272B rows, 16B-aligned b128
#define PPIT 76    // attn P tile: 152B rows, b64 frag reads, conflict-free
#define GP   40    // GEMM tiles: 80B rows, 16B-aligned b128

// ---------------------------------------------------------------------------
// fp32 -> f16 convert of X, W1, W2; mask is scanned for nonzero only.
// ---------------------------------------------------------------------------
__global__ __launch_bounds__(256) void cvt_f16(const float* __restrict__ X,
                                               const float* __restrict__ W1,
                                               const float* __restrict__ W2,
                                               const float* __restrict__ M,
                                               f16* __restrict__ Xh,
                                               f16* __restrict__ W1h,
                                               f16* __restrict__ W2h,
                                               int* __restrict__ flag)
{
    int tid = blockIdx.x * 256 + threadIdx.x;
    if (blockIdx.y == 3) {   // mask: flag-only scan
        if (tid < 1048576) {
            float4 v = ((const float4*)M)[tid];
            bool nz = (v.x != 0.f) || (v.y != 0.f) || (v.z != 0.f) || (v.w != 0.f);
            if (__any(nz) && (threadIdx.x & 63) == 0) atomicOr(flag, 1);
        }
        return;
    }
    const float* src; f16* dst; int n4;
    switch (blockIdx.y) {
        case 0:  src = X;  dst = Xh;  n4 = 786432;  break;
        case 1:  src = W1; dst = W1h; n4 = 442368;  break;
        default: src = W2; dst = W2h; n4 = 147456;  break;
    }
    if (tid < n4) {
        float4 v = ((const float4*)src)[tid];
        f16x4 o = {(f16)v.x, (f16)v.y, (f16)v.z, (f16)v.w};
        ((f16x4*)dst)[tid] = o;
    }
}

// ---------------------------------------------------------------------------
// QKV GEMM, f16 inputs, reg-prefetched staging. 128x128 tile, 4 waves 2x2,
// BK=32. Epilogue: bias, l2-norm Q/K rows, fold exp(min(ls,MAX))*LOG2E into Q.
// ---------------------------------------------------------------------------
__global__ __launch_bounds__(256, 3) void qkv_gemm(const f16* __restrict__ Xh,
                                                   const f16* __restrict__ Wh,
                                                   const float* __restrict__ bias,
                                                   const float* __restrict__ logit_scale,
                                                   f16* __restrict__ qkv16)
{
    __shared__ f16 As[128 * GP];
    __shared__ f16 Bs[128 * GP];
    const int t    = threadIdx.x;
    const int w    = t >> 6;
    const int lane = t & 63;
    const int quad = lane >> 4;
    const int sub  = lane & 15;
    const int wm   = w & 1, wn = w >> 1;
    const int f0   = blockIdx.x * 128;
    const int m0   = blockIdx.y * 128;
    const int srow = t >> 1;
    const int sk   = (t & 1) * 16;

    const f16* ag = Xh + (size_t)(m0 + srow) * CH + sk;
    const f16* bg = Wh + (size_t)(f0 + srow) * CH + sk;
    f16x8 a0 = *(const f16x8*)(ag);
    f16x8 a1 = *(const f16x8*)(ag + 8);
    f16x8 b0 = *(const f16x8*)(bg);
    f16x8 b1 = *(const f16x8*)(bg + 8);

    f32x4 acc[4][4];
#pragma unroll
    for (int i = 0; i < 4; ++i)
#pragma unroll
        for (int j = 0; j < 4; ++j) acc[i][j] = (f32x4){0.f, 0.f, 0.f, 0.f};

    for (int k0 = 0; k0 < CH; k0 += 32) {
        __syncthreads();
        *(f16x8*)&As[srow * GP + sk + 0] = a0;
        *(f16x8*)&As[srow * GP + sk + 8] = a1;
        *(f16x8*)&Bs[srow * GP + sk + 0] = b0;
        *(f16x8*)&Bs[srow * GP + sk + 8] = b1;
        __syncthreads();
        if (k0 + 32 < CH) {
            a0 = *(const f16x8*)(ag + k0 + 32);
            a1 = *(const f16x8*)(ag + k0 + 40);
            b0 = *(const f16x8*)(bg + k0 + 32);
            b1 = *(const f16x8*)(bg + k0 + 40);
        }
        f16x8 af[4], bf[4];
#pragma unroll
        for (int i = 0; i < 4; ++i) {
            af[i] = *(const f16x8*)&As[(wm * 64 + i * 16 + sub) * GP + quad * 8];
            bf[i] = *(const f16x8*)&Bs[(wn * 64 + i * 16 + sub) * GP + quad * 8];
        }
#pragma unroll
        for (int i = 0; i < 4; ++i)
#pragma unroll
            for (int j = 0; j < 4; ++j)
                acc[i][j] = __builtin_amdgcn_mfma_f32_16x16x32_f16(af[i], bf[j], acc[i][j], 0, 0, 0);
    }

    const int t3 = f0 / CH;
    const int h  = ((f0 + wn * 64) % CH) >> 6;
    f16* dst = qkv16 + (size_t)t3 * QSZ;
    float lsv = (t3 == 0) ? __expf(fminf(logit_scale[h], LSMAX)) * LOG2E : 1.0f;
    float bb[4];
#pragma unroll
    for (int j = 0; j < 4; ++j) bb[j] = bias[f0 + wn * 64 + j * 16 + sub];
#pragma unroll
    for (int i = 0; i < 4; ++i) {
#pragma unroll
        for (int r = 0; r < 4; ++r) {
            int m = m0 + wm * 64 + i * 16 + quad * 4 + r;
            int n = m >> 11, l = m & 2047;
            float v[4];
#pragma unroll
            for (int j = 0; j < 4; ++j) v[j] = acc[i][j][r] + bb[j];
            float scale = 1.0f;
            if (t3 < 2) {
                float ss = v[0] * v[0] + v[1] * v[1] + v[2] * v[2] + v[3] * v[3];
#pragma unroll
                for (int mk = 1; mk < 16; mk <<= 1) ss += __shfl_xor(ss, mk, 64);
                scale = 1.0f / fmaxf(sqrtf(ss), 1e-12f);
                if (t3 == 0) scale *= lsv;
            }
            f16* drow = dst + (((size_t)n * NH + h) * SEQ + l) * HD;
#pragma unroll
            for (int j = 0; j < 4; ++j)
                drow[j * 16 + sub] = (f16)(v[j] * scale);
        }
    }
}

// ---------------------------------------------------------------------------
// Flash attention, f16 MFMA, KC=128. K fragments direct from global, but
// SOFTWARE-PIPELINED: half0 of the next chunk's K-frags is prefetched into
// registers during the current chunk's softmax/PV; half1 is loaded per-iter
// in two 4-frag batches issued under the half0-MFMA + V-store shadow.
// V double-buffered in LDS (one barrier/iter). launch_bounds(256,4) pins
// VGPR<=128 to stay at 4 waves/SIMD.
// ---------------------------------------------------------------------------
__global__ __launch_bounds__(256, 4) void attn(const f16* __restrict__ Qh,
                                               const f16* __restrict__ Kh,
                                               const f16* __restrict__ Vh,
                                               const float* __restrict__ M32,
                                               const float* __restrict__ lscale,
                                               const int* __restrict__ flag,
                                               f16* __restrict__ Og)
{
    __shared__ f16 Vt[2][64 * VP];  // [d][key 0..127] x2   34.8 KB
    __shared__ f16 Ps[64 * PPIT];   // P tile                9.7 KB

    const int t    = threadIdx.x;
    const int w    = t >> 6;
    const int lane = t & 63;
    const int quad = lane >> 4;
    const int sub  = lane & 15;
    const int qb   = blockIdx.x * 64;
    const int h    = blockIdx.y, n = blockIdx.z;
    const bool has_mask = (*flag) != 0;

    const f16* Qg = Qh + ((size_t)(n * NH + h) * SEQ + qb) * HD;
    const f16* Kg = Kh + (size_t)(n * NH + h) * SEQ * HD;
    const f16* Vg = Vh + (size_t)(n * NH + h) * SEQ * HD;
    const float* Mg = M32 + (size_t)(qb + w * 16 + quad * 4) * SEQ;

    // Q fragments direct from global (A-layout: m=sub row, k=quad*8..)
    f16x8 qf0 = *(const f16x8*)&Qg[(w * 16 + sub) * 64 + quad * 8];
    f16x8 qf1 = *(const f16x8*)&Qg[(w * 16 + sub) * 64 + 32 + quad * 8];

    // V chunk 0 -> regs -> buf0; prefetch chunk 1 into regs
    f16x8 vr0, vr1, vr2, vr3;
    {
        const f16* vp = Vg + (2 * lane) * 64 + w * 16;
        vr0 = *(const f16x8*)(vp + 0);
        vr1 = *(const f16x8*)(vp + 8);
        vr2 = *(const f16x8*)(vp + 64);
        vr3 = *(const f16x8*)(vp + 72);
    }
#pragma unroll
    for (int j = 0; j < 8; ++j) {
        *(f16x2*)&Vt[0][(w * 16 + j) * VP + 2 * lane]     = (f16x2){vr0[j], vr2[j]};
        *(f16x2*)&Vt[0][(w * 16 + 8 + j) * VP + 2 * lane] = (f16x2){vr1[j], vr3[j]};
    }
    {
        const f16* vp = Vg + (128 + 2 * lane) * 64 + w * 16;
        vr0 = *(const f16x8*)(vp + 0);
        vr1 = *(const f16x8*)(vp + 8);
        vr2 = *(const f16x8*)(vp + 64);
        vr3 = *(const f16x8*)(vp + 72);
    }
    // prefetch chunk 0, half0 K-frags (B-layout: col=sub, k=quad*8..)
    f16x8 kf0[8];
#pragma unroll
    for (int ct = 0; ct < 8; ++ct)
        kf0[ct] = *(const f16x8*)&Kg[(ct * 16 + sub) * 64 + quad * 8];

    __syncthreads();   // buf0 visible

    const f16x8 ones = {(f16)1.f, (f16)1.f, (f16)1.f, (f16)1.f,
                        (f16)1.f, (f16)1.f, (f16)1.f, (f16)1.f};
    f32x4 o[4];
    f32x4 l_acc = (f32x4){0.f, 0.f, 0.f, 0.f};
    float m_run[4];
#pragma unroll
    for (int dt = 0; dt < 4; ++dt) o[dt] = (f32x4){0.f, 0.f, 0.f, 0.f};
#pragma unroll
    for (int r = 0; r < 4; ++r) m_run[r] = -1e30f;

    const int NITER = SEQ / 128;
    for (int c = 0; c < NITER; ++c) {
        const int c0 = c * 128;
        const int cur = c & 1, nxt = cur ^ 1;
        if (c > 0) __syncthreads();   // prev iter's readers of buf[nxt] done

        const f16* kbase = Kg + (size_t)c0 * 64;

        // V restage for chunk c+1 (frees vr regs early)
        if (c + 1 < NITER) {
#pragma unroll
            for (int j = 0; j < 8; ++j) {
                *(f16x2*)&Vt[nxt][(w * 16 + j) * VP + 2 * lane]     = (f16x2){vr0[j], vr2[j]};
                *(f16x2*)&Vt[nxt][(w * 16 + 8 + j) * VP + 2 * lane] = (f16x2){vr1[j], vr3[j]};
            }
        }

        // half1 K-frags, batch A (issue before half0 MFMAs)
        f16x8 kfA[4], kfB[4];
#pragma unroll
        for (int ct = 0; ct < 4; ++ct)
            kfA[ct] = *(const f16x8*)&kbase[(ct * 16 + sub) * 64 + 32 + quad * 8];

        // S half0: 8 MFMAs on prefetched kf0
        f32x4 s[8];
#pragma unroll
        for (int ct = 0; ct < 8; ++ct) {
            f32x4 a = (f32x4){0.f, 0.f, 0.f, 0.f};
            s[ct] = __builtin_amdgcn_mfma_f32_16x16x32_f16(qf0, kf0[ct], a, 0, 0, 0);
        }
        // half1 batch B issue
#pragma unroll
        for (int ct = 0; ct < 4; ++ct)
            kfB[ct] = *(const f16x8*)&kbase[((ct + 4) * 16 + sub) * 64 + 32 + quad * 8];
        // S half1, batch A
#pragma unroll
        for (int ct = 0; ct < 4; ++ct)
            s[ct] = __builtin_amdgcn_mfma_f32_16x16x32_f16(qf1, kfA[ct], s[ct], 0, 0, 0);
        // prefetch NEXT chunk half0 into kf0 (drains during softmax/PV)
        if (c + 1 < NITER) {
            const f16* kn = Kg + (size_t)(c0 + 128) * 64;
#pragma unroll
            for (int ct = 0; ct < 8; ++ct)
                kf0[ct] = *(const f16x8*)&kn[(ct * 16 + sub) * 64 + quad * 8];
        }
        // S half1, batch B
#pragma unroll
        for (int ct = 0; ct < 4; ++ct)
            s[ct + 4] = __builtin_amdgcn_mfma_f32_16x16x32_f16(qf1, kfB[ct], s[ct + 4], 0, 0, 0);

        if (has_mask) {   // rare path: fp32 mask direct, scaled to log2 domain
#pragma unroll
            for (int ct = 0; ct < 8; ++ct)
#pragma unroll
                for (int r = 0; r < 4; ++r)
                    s[ct][r] += LOG2E * Mg[(size_t)r * SEQ + c0 + ct * 16 + sub];
        }
        // row max over 128 cols + running, packed-f16 16-lane butterfly
        float mnew[4];
#pragma unroll
        for (int r = 0; r < 4; ++r) {
            float a01 = fmaxf(s[0][r], s[1][r]), a23 = fmaxf(s[2][r], s[3][r]);
            float a45 = fmaxf(s[4][r], s[5][r]), a67 = fmaxf(s[6][r], s[7][r]);
            mnew[r] = fmaxf(fmaxf(fmaxf(a01, a23), fmaxf(a45, a67)), m_run[r]);
        }
        {
            union { f16x2 h; int i; } p0, p1, v0, v1;
            p0.h = (f16x2){(f16)mnew[0], (f16)mnew[1]};
            p1.h = (f16x2){(f16)mnew[2], (f16)mnew[3]};
#pragma unroll
            for (int mk = 1; mk < 16; mk <<= 1) {
                v0.i = __shfl_xor(p0.i, mk, 64);
                v1.i = __shfl_xor(p1.i, mk, 64);
                p0.h = __builtin_elementwise_max(p0.h, v0.h);
                p1.h = __builtin_elementwise_max(p1.h, v1.h);
            }
            mnew[0] = (float)p0.h[0]; mnew[1] = (float)p0.h[1];
            mnew[2] = (float)p1.h[0]; mnew[3] = (float)p1.h[1];
        }
        float alpha[4];
#pragma unroll
        for (int r = 0; r < 4; ++r) {
            alpha[r] = exp2f(m_run[r] - mnew[r]);
            m_run[r] = mnew[r];
        }
        // rescale O and l
#pragma unroll
        for (int dt = 0; dt < 4; ++dt)
#pragma unroll
            for (int r = 0; r < 4; ++r) o[dt][r] *= alpha[r];
#pragma unroll
        for (int r = 0; r < 4; ++r) l_acc[r] *= alpha[r];

        // V prefetch for chunk c+2 (issued here; consumed at next-iter top)
        if (c + 2 < NITER) {
            const f16* vp = Vg + ((c + 2) * 128 + 2 * lane) * 64 + w * 16;
            vr0 = *(const f16x8*)(vp + 0);
            vr1 = *(const f16x8*)(vp + 8);
            vr2 = *(const f16x8*)(vp + 64);
            vr3 = *(const f16x8*)(vp + 72);
        }

        // two 64-key halves through the shared P tile (wave-private rows)
#pragma unroll
        for (int hf = 0; hf < 2; ++hf) {
#pragma unroll
            for (int ct = 0; ct < 4; ++ct)
#pragma unroll
                for (int r = 0; r < 4; ++r) {
                    float p = exp2f(s[hf * 4 + ct][r] - mnew[r]);
                    Ps[(w * 16 + quad * 4 + r) * PPIT + ct * 16 + sub] = (f16)p;
                }
            f16x4 p00 = *(const f16x4*)&Ps[(w * 16 + sub) * PPIT + quad * 8];
            f16x4 p01 = *(const f16x4*)&Ps[(w * 16 + sub) * PPIT + quad * 8 + 4];
            f16x4 p10 = *(const f16x4*)&Ps[(w * 16 + sub) * PPIT + 32 + quad * 8];
            f16x4 p11 = *(const f16x4*)&Ps[(w * 16 + sub) * PPIT + 32 + quad * 8 + 4];
            f16x8 pf0 = {p00[0], p00[1], p00[2], p00[3], p01[0], p01[1], p01[2], p01[3]};
            f16x8 pf1 = {p10[0], p10[1], p10[2], p10[3], p11[0], p11[1], p11[2], p11[3]};
            l_acc = __builtin_amdgcn_mfma_f32_16x16x32_f16(pf0, ones, l_acc, 0, 0, 0);
            l_acc = __builtin_amdgcn_mfma_f32_16x16x32_f16(pf1, ones, l_acc, 0, 0, 0);
#pragma unroll
            for (int dt = 0; dt < 4; ++dt) {
                f16x8 vf0 = *(const f16x8*)&Vt[cur][(dt * 16 + sub) * VP + hf * 64 + quad * 8];
                f16x8 vf1 = *(const f16x8*)&Vt[cur][(dt * 16 + sub) * VP + hf * 64 + 32 + quad * 8];
                o[dt] = __builtin_amdgcn_mfma_f32_16x16x32_f16(pf0, vf0, o[dt], 0, 0, 0);
                o[dt] = __builtin_amdgcn_mfma_f32_16x16x32_f16(pf1, vf1, o[dt], 0, 0, 0);
            }
        }
    }
    // epilogue
    float lsc = lscale[h];
#pragma unroll
    for (int r = 0; r < 4; ++r) {
        float inv = lsc / l_acc[r];
        int q = qb + w * 16 + quad * 4 + r;
#pragma unroll
        for (int dt = 0; dt < 4; ++dt)
            Og[((size_t)n * SEQ + q) * CH + h * 64 + dt * 16 + sub] =
                (f16)(o[dt][r] * inv);
    }
}

// ---------------------------------------------------------------------------
// Output projection, f16 inputs, reg-prefetched staging. fp32 out.
// ---------------------------------------------------------------------------
__global__ __launch_bounds__(256, 3) void out_gemm(const f16* __restrict__ A,
                                                   const f16* __restrict__ Wh,
                                                   const float* __restrict__ bias,
                                                   float* __restrict__ out)
{
    __shared__ f16 As[128 * GP];
    __shared__ f16 Bs[128 * GP];
    const int t    = threadIdx.x;
    const int w    = t >> 6;
    const int lane = t & 63;
    const int quad = lane >> 4;
    const int sub  = lane & 15;
    const int wm   = w & 1, wn = w >> 1;
    const int f0   = blockIdx.x * 128;
    const int m0   = blockIdx.y * 128;
    const int srow = t >> 1;
    const int sk   = (t & 1) * 16;

    const f16* ag = A + (size_t)(m0 + srow) * CH + sk;
    const f16* bg = Wh + (size_t)(f0 + srow) * CH + sk;
    f16x8 a0 = *(const f16x8*)(ag);
    f16x8 a1 = *(const f16x8*)(ag + 8);
    f16x8 b0 = *(const f16x8*)(bg);
    f16x8 b1 = *(const f16x8*)(bg + 8);

    f32x4 acc[4][4];
#pragma unroll
    for (int i = 0; i < 4; ++i)
#pragma unroll
        for (int j = 0; j < 4; ++j) acc[i][j] = (f32x4){0.f, 0.f, 0.f, 0.f};

    for (int k0 = 0; k0 < CH; k0 += 32) {
        __syncthreads();
        *(f16x8*)&As[srow * GP + sk + 0] = a0;
        *(f16x8*)&As[srow * GP + sk + 8] = a1;
        *(f16x8*)&Bs[srow * GP + sk + 0] = b0;
        *(f16x8*)&Bs[srow * GP + sk + 8] = b1;
        __syncthreads();
        if (k0 + 32 < CH) {
            a0 = *(const f16x8*)(ag + k0 + 32);
            a1 = *(const f16x8*)(ag + k0 + 40);
            b0 = *(const f16x8*)(bg + k0 + 32);
            b1 = *(const f16x8*)(bg + k0 + 40);
        }
        f16x8 af[4], bf[4];
#pragma unroll
        for (int i = 0; i < 4; ++i) {
            af[i] = *(const f16x8*)&As[(wm * 64 + i * 16 + sub) * GP + quad * 8];
            bf[i] = *(const f16x8*)&Bs[(wn * 64 + i * 16 + sub) * GP + quad * 8];
        }
#pragma unroll
        for (int i = 0; i < 4; ++i)
#pragma unroll
            for (int j = 0; j < 4; ++j)
                acc[i][j] = __builtin_amdgcn_mfma_f32_16x16x32_f16(af[i], bf[j], acc[i][j], 0, 0, 0);
    }
    float bb[4];
#pragma unroll
    for (int j = 0; j < 4; ++j) bb[j] = bias[f0 + wn * 64 + j * 16 + sub];
#pragma unroll
    for (int i = 0; i < 4; ++i)
#pragma unroll
        for (int r = 0; r < 4; ++r) {
            int m = m0 + wm * 64 + i * 16 + quad * 4 + r;
            float* orow = out + (size_t)m * CH + f0 + wn * 64;
#pragma unroll
            for (int j = 0; j < 4; ++j)
                orow[j * 16 + sub] = acc[i][j][r] + bb[j];
        }
}

extern "C" void kernel_launch(void* const* d_in, const int* in_sizes, int n_in,
                              void* d_out, int out_size, void* d_ws, size_t ws_size,
                              hipStream_t stream) {
    const float* x    = (const float*)d_in[0];
    const float* w1   = (const float*)d_in[1];
    const float* b1   = (const float*)d_in[2];
    const float* ls   = (const float*)d_in[3];
    const float* lrn  = (const float*)d_in[4];
    const float* w2   = (const float*)d_in[5];
    const float* b2   = (const float*)d_in[6];
    const float* msk  = (const float*)d_in[7];
    f16*   ws16 = (f16*)d_ws;
    int*   flag = (int*)(ws16 + FLAGO);
    float* out  = (float*)d_out;

    (void)hipMemsetAsync(flag, 0, 4, stream);
    hipLaunchKernelGGL(cvt_f16, dim3(4096, 4), dim3(256), 0, stream,
                       x, w1, w2, msk,
                       ws16 + XHOFF, ws16 + W1OFF, ws16 + W2OFF, flag);
    hipLaunchKernelGGL(qkv_gemm, dim3(F3 / 128, (NB * SEQ) / 128), dim3(256), 0, stream,
                       ws16 + XHOFF, ws16 + W1OFF, b1, ls, ws16);
    hipLaunchKernelGGL(attn, dim3(SEQ / 64, NH, NB), dim3(256), 0, stream,
                       ws16, ws16 + QSZ, ws16 + 2 * QSZ, msk, lrn, flag,
                       ws16 + OATT);
    hipLaunchKernelGGL(out_gemm, dim3(CH / 128, (NB * SEQ) / 128), dim3(256), 0, stream,
                       ws16 + OATT, ws16 + W2OFF, b2, out);
}

// Round 10
// 241.193 us; speedup vs baseline: 1.1416x; 1.1416x over previous
//
#include <hip/hip_runtime.h>
#include <math.h>

// Problem constants
#define NB   2
#define SEQ  2048
#define CH   768
#define NH   12
#define HD   64
#define F3   2304
#define LSMAX 4.605170185988092f
#define LOG2E 1.4426950408889634f

typedef _Float16 f16;
typedef __attribute__((ext_vector_type(8))) _Float16 f16x8;
typedef __attribute__((ext_vector_type(4))) _Float16 f16x4;
typedef __attribute__((ext_vector_type(2))) _Float16 f16x2;
typedef __attribute__((ext_vector_type(4))) float f32x4;

// f16 workspace layout (units: f16 elements)
#define QSZ   3145728                 // per Q/K/V tensor
#define OATT  (3 * QSZ)               // attn out [N,L,C] f16 (3145728)
#define FLAGO 12582912                // int flag: mask nonzero

// LDS pitches
#define KP   72    // attn K tile: 144B rows, 16B-aligned b128
#define VP   136   // attn Vt tile (128 keys): 272B rows, 16B-aligned b128
#define PPIT 76    // attn Q/P tile: 152B rows, b64 frag reads
#define GP   40    // GEMM tiles: 80B rows, 16B-aligned b128

// ---------------------------------------------------------------------------
// Mask nonzero scan (flag pre-zeroed by memset). Conversion work now lives
// inside the GEMM staging paths — no f16 copies of X/W1/W2 exist anymore.
// ---------------------------------------------------------------------------
__global__ __launch_bounds__(256) void mask_scan(const float* __restrict__ M,
                                                 int* __restrict__ flag)
{
    int tid = blockIdx.x * 256 + threadIdx.x;
    float4 v = ((const float4*)M)[tid];
    bool nz = (v.x != 0.f) || (v.y != 0.f) || (v.z != 0.f) || (v.w != 0.f);
    if (__any(nz) && (threadIdx.x & 63) == 0) atomicOr(flag, 1);
}

// ---------------------------------------------------------------------------
// QKV GEMM: fp32 X/W1 in global, converted to f16 during LDS staging
// (removes the separate cvt kernel + its HBM round-trip). 128x128 tile,
// 4 waves 2x2, BK=32. Epilogue: bias, l2-norm Q/K rows, fold
// exp(min(ls,MAX))*LOG2E into Q (log2-domain softmax downstream).
// ---------------------------------------------------------------------------
__global__ __launch_bounds__(256, 3) void qkv_gemm(const float* __restrict__ X,
                                                   const float* __restrict__ W,
                                                   const float* __restrict__ bias,
                                                   const float* __restrict__ logit_scale,
                                                   f16* __restrict__ qkv16)
{
    __shared__ f16 As[128 * GP];
    __shared__ f16 Bs[128 * GP];
    const int t    = threadIdx.x;
    const int w    = t >> 6;
    const int lane = t & 63;
    const int quad = lane >> 4;
    const int sub  = lane & 15;
    const int wm   = w & 1, wn = w >> 1;
    const int f0   = blockIdx.x * 128;
    const int m0   = blockIdx.y * 128;
    const int srow = t >> 1;
    const int sk   = (t & 1) * 16;

    const float* ag = X + (size_t)(m0 + srow) * CH + sk;
    const float* bg = W + (size_t)(f0 + srow) * CH + sk;
    float4 a4[4], b4[4];
#pragma unroll
    for (int j = 0; j < 4; ++j) {
        a4[j] = *(const float4*)(ag + 4 * j);
        b4[j] = *(const float4*)(bg + 4 * j);
    }

    f32x4 acc[4][4];
#pragma unroll
    for (int i = 0; i < 4; ++i)
#pragma unroll
        for (int j = 0; j < 4; ++j) acc[i][j] = (f32x4){0.f, 0.f, 0.f, 0.f};

    for (int k0 = 0; k0 < CH; k0 += 32) {
        __syncthreads();
#pragma unroll
        for (int j = 0; j < 4; ++j) {
            f16x4 av = {(f16)a4[j].x, (f16)a4[j].y, (f16)a4[j].z, (f16)a4[j].w};
            f16x4 bv = {(f16)b4[j].x, (f16)b4[j].y, (f16)b4[j].z, (f16)b4[j].w};
            *(f16x4*)&As[srow * GP + sk + 4 * j] = av;
            *(f16x4*)&Bs[srow * GP + sk + 4 * j] = bv;
        }
        __syncthreads();
        if (k0 + 32 < CH) {
#pragma unroll
            for (int j = 0; j < 4; ++j) {
                a4[j] = *(const float4*)(ag + k0 + 32 + 4 * j);
                b4[j] = *(const float4*)(bg + k0 + 32 + 4 * j);
            }
        }
        f16x8 af[4], bf[4];
#pragma unroll
        for (int i = 0; i < 4; ++i) {
            af[i] = *(const f16x8*)&As[(wm * 64 + i * 16 + sub) * GP + quad * 8];
            bf[i] = *(const f16x8*)&Bs[(wn * 64 + i * 16 + sub) * GP + quad * 8];
        }
#pragma unroll
        for (int i = 0; i < 4; ++i)
#pragma unroll
            for (int j = 0; j < 4; ++j)
                acc[i][j] = __builtin_amdgcn_mfma_f32_16x16x32_f16(af[i], bf[j], acc[i][j], 0, 0, 0);
    }

    const int t3 = f0 / CH;                       // 0=q,1=k,2=v (block-uniform)
    const int h  = ((f0 + wn * 64) % CH) >> 6;    // wave-uniform head
    f16* dst = qkv16 + (size_t)t3 * QSZ;
    float lsv = (t3 == 0) ? __expf(fminf(logit_scale[h], LSMAX)) * LOG2E : 1.0f;
    float bb[4];
#pragma unroll
    for (int j = 0; j < 4; ++j) bb[j] = bias[f0 + wn * 64 + j * 16 + sub];
#pragma unroll
    for (int i = 0; i < 4; ++i) {
#pragma unroll
        for (int r = 0; r < 4; ++r) {
            int m = m0 + wm * 64 + i * 16 + quad * 4 + r;
            int n = m >> 11, l = m & 2047;
            float v[4];
#pragma unroll
            for (int j = 0; j < 4; ++j) v[j] = acc[i][j][r] + bb[j];
            float scale = 1.0f;
            if (t3 < 2) {
                float ss = v[0] * v[0] + v[1] * v[1] + v[2] * v[2] + v[3] * v[3];
#pragma unroll
                for (int mk = 1; mk < 16; mk <<= 1) ss += __shfl_xor(ss, mk, 64);
                scale = 1.0f / fmaxf(sqrtf(ss), 1e-12f);
                if (t3 == 0) scale *= lsv;
            }
            f16* drow = dst + (((size_t)n * NH + h) * SEQ + l) * HD;
#pragma unroll
            for (int j = 0; j < 4; ++j)
                drow[j * 16 + sub] = (f16)(v[j] * scale);
        }
    }
}

// ---------------------------------------------------------------------------
// Flash attention (R7 winner, reverted verbatim): f16 MFMA, KC=128 keys per
// iteration (16 iters), log2-domain softmax, single-buffer K/V LDS + full
// register prefetch, P in two 64-key halves through one shared Q/P tile,
// l via ones-MFMA.
// ---------------------------------------------------------------------------
__global__ __launch_bounds__(256, 3) void attn(const f16* __restrict__ Qh,
                                               const f16* __restrict__ Kh,
                                               const f16* __restrict__ Vh,
                                               const float* __restrict__ M32,
                                               const float* __restrict__ lscale,
                                               const int* __restrict__ flag,
                                               f16* __restrict__ Og)
{
    __shared__ f16 Ks[128 * KP];    // [key][d]          18.4 KB
    __shared__ f16 Vt[64 * VP];     // [d][key 0..127]   17.4 KB
    __shared__ f16 QP[64 * PPIT];   // Q tile -> P tile   9.7 KB

    const int t    = threadIdx.x;
    const int w    = t >> 6;
    const int lane = t & 63;
    const int quad = lane >> 4;
    const int sub  = lane & 15;
    const int qb   = blockIdx.x * 64;
    const int h    = blockIdx.y, n = blockIdx.z;
    const bool has_mask = (*flag) != 0;

    const f16* Qg = Qh + ((size_t)(n * NH + h) * SEQ + qb) * HD;
    const f16* Kg = Kh + (size_t)(n * NH + h) * SEQ * HD;
    const f16* Vg = Vh + (size_t)(n * NH + h) * SEQ * HD;
    const float* Mg = M32 + (size_t)(qb + w * 16 + quad * 4) * SEQ;

    // stage Q
#pragma unroll
    for (int rep = 0; rep < 2; ++rep) {
        int id = rep * 256 + t;
        int row = id >> 3, c8 = id & 7;
        f16x8 v = *(const f16x8*)&Qg[row * 64 + c8 * 8];
        *(f16x4*)&QP[row * PPIT + c8 * 8 + 0] = (f16x4){v[0], v[1], v[2], v[3]};
        *(f16x4*)&QP[row * PPIT + c8 * 8 + 4] = (f16x4){v[4], v[5], v[6], v[7]};
    }

    // prefetch chunk 0: K 4 b128 (row t>>1, colblock (t&1)*32),
    //                   V 4 b128 (keys 2*lane, 2*lane+1; d-slice w*16..+16)
    const int krow = t >> 1;
    const int kcb  = (t & 1) * 32;
    f16x8 kr0, kr1, kr2, kr3, vr0, vr1, vr2, vr3;
    {
        const f16* kp = Kg + krow * 64 + kcb;
        kr0 = *(const f16x8*)(kp + 0);
        kr1 = *(const f16x8*)(kp + 8);
        kr2 = *(const f16x8*)(kp + 16);
        kr3 = *(const f16x8*)(kp + 24);
        const f16* vp = Vg + (2 * lane) * 64 + w * 16;
        vr0 = *(const f16x8*)(vp + 0);
        vr1 = *(const f16x8*)(vp + 8);
        vr2 = *(const f16x8*)(vp + 64);
        vr3 = *(const f16x8*)(vp + 72);
    }

    __syncthreads();   // Q staged
    f16x8 qf0, qf1;
    {
        f16x4 l0 = *(const f16x4*)&QP[(w * 16 + sub) * PPIT + quad * 8];
        f16x4 l1 = *(const f16x4*)&QP[(w * 16 + sub) * PPIT + quad * 8 + 4];
        f16x4 l2 = *(const f16x4*)&QP[(w * 16 + sub) * PPIT + 32 + quad * 8];
        f16x4 l3 = *(const f16x4*)&QP[(w * 16 + sub) * PPIT + 32 + quad * 8 + 4];
        qf0 = (f16x8){l0[0], l0[1], l0[2], l0[3], l1[0], l1[1], l1[2], l1[3]};
        qf1 = (f16x8){l2[0], l2[1], l2[2], l2[3], l3[0], l3[1], l3[2], l3[3]};
    }

    // store chunk 0 into LDS
    {
        f16* kd = &Ks[krow * KP + kcb];
        *(f16x8*)(kd + 0)  = kr0;
        *(f16x8*)(kd + 8)  = kr1;
        *(f16x8*)(kd + 16) = kr2;
        *(f16x8*)(kd + 24) = kr3;
#pragma unroll
        for (int j = 0; j < 8; ++j) {
            *(f16x2*)&Vt[(w * 16 + j) * VP + 2 * lane]     = (f16x2){vr0[j], vr2[j]};
            *(f16x2*)&Vt[(w * 16 + 8 + j) * VP + 2 * lane] = (f16x2){vr1[j], vr3[j]};
        }
    }
    __syncthreads();

    const f16x8 ones = {(f16)1.f, (f16)1.f, (f16)1.f, (f16)1.f,
                        (f16)1.f, (f16)1.f, (f16)1.f, (f16)1.f};
    f32x4 o[4];
    f32x4 l_acc = (f32x4){0.f, 0.f, 0.f, 0.f};
    float m_run[4];
#pragma unroll
    for (int dt = 0; dt < 4; ++dt) o[dt] = (f32x4){0.f, 0.f, 0.f, 0.f};
#pragma unroll
    for (int r = 0; r < 4; ++r) m_run[r] = -1e30f;

    const int NITER = SEQ / 128;
    for (int c = 0; c < NITER; ++c) {
        const int c0 = c * 128;
        // prefetch next chunk (fully overlapped with compute below)
        if (c + 1 < NITER) {
            const f16* kp = Kg + (c0 + 128 + krow) * 64 + kcb;
            kr0 = *(const f16x8*)(kp + 0);
            kr1 = *(const f16x8*)(kp + 8);
            kr2 = *(const f16x8*)(kp + 16);
            kr3 = *(const f16x8*)(kp + 24);
            const f16* vp = Vg + (c0 + 128 + 2 * lane) * 64 + w * 16;
            vr0 = *(const f16x8*)(vp + 0);
            vr1 = *(const f16x8*)(vp + 8);
            vr2 = *(const f16x8*)(vp + 64);
            vr3 = *(const f16x8*)(vp + 72);
        }

        // S = Q.K^T over 128 keys (8 column tiles)
        f32x4 s[8];
#pragma unroll
        for (int ct = 0; ct < 8; ++ct) {
            f16x8 kf0 = *(const f16x8*)&Ks[(ct * 16 + sub) * KP + quad * 8];
            f16x8 kf1 = *(const f16x8*)&Ks[(ct * 16 + sub) * KP + 32 + quad * 8];
            f32x4 a = (f32x4){0.f, 0.f, 0.f, 0.f};
            a = __builtin_amdgcn_mfma_f32_16x16x32_f16(qf0, kf0, a, 0, 0, 0);
            a = __builtin_amdgcn_mfma_f32_16x16x32_f16(qf1, kf1, a, 0, 0, 0);
            s[ct] = a;
        }
        if (has_mask) {   // rare path: fp32 mask direct, scaled to log2 domain
#pragma unroll
            for (int ct = 0; ct < 8; ++ct)
#pragma unroll
                for (int r = 0; r < 4; ++r)
                    s[ct][r] += LOG2E * Mg[(size_t)r * SEQ + c0 + ct * 16 + sub];
        }
        // row max over 128 cols + running, packed-f16 16-lane butterfly
        float mnew[4];
#pragma unroll
        for (int r = 0; r < 4; ++r) {
            float a01 = fmaxf(s[0][r], s[1][r]), a23 = fmaxf(s[2][r], s[3][r]);
            float a45 = fmaxf(s[4][r], s[5][r]), a67 = fmaxf(s[6][r], s[7][r]);
            mnew[r] = fmaxf(fmaxf(fmaxf(a01, a23), fmaxf(a45, a67)), m_run[r]);
        }
        {
            union { f16x2 h; int i; } p0, p1, v0, v1;
            p0.h = (f16x2){(f16)mnew[0], (f16)mnew[1]};
            p1.h = (f16x2){(f16)mnew[2], (f16)mnew[3]};
#pragma unroll
            for (int mk = 1; mk < 16; mk <<= 1) {
                v0.i = __shfl_xor(p0.i, mk, 64);
                v1.i = __shfl_xor(p1.i, mk, 64);
                p0.h = __builtin_elementwise_max(p0.h, v0.h);
                p1.h = __builtin_elementwise_max(p1.h, v1.h);
            }
            mnew[0] = (float)p0.h[0]; mnew[1] = (float)p0.h[1];
            mnew[2] = (float)p1.h[0]; mnew[3] = (float)p1.h[1];
        }
        float alpha[4];
#pragma unroll
        for (int r = 0; r < 4; ++r) {
            alpha[r] = exp2f(m_run[r] - mnew[r]);
            m_run[r] = mnew[r];
        }
        // rescale O and l
#pragma unroll
        for (int dt = 0; dt < 4; ++dt)
#pragma unroll
            for (int r = 0; r < 4; ++r) o[dt][r] *= alpha[r];
#pragma unroll
        for (int r = 0; r < 4; ++r) l_acc[r] *= alpha[r];

        // two 64-key halves through the shared P tile (wave-private rows)
#pragma unroll
        for (int hf = 0; hf < 2; ++hf) {
#pragma unroll
            for (int ct = 0; ct < 4; ++ct)
#pragma unroll
                for (int r = 0; r < 4; ++r) {
                    float p = exp2f(s[hf * 4 + ct][r] - mnew[r]);
                    QP[(w * 16 + quad * 4 + r) * PPIT + ct * 16 + sub] = (f16)p;
                }
            f16x4 p00 = *(const f16x4*)&QP[(w * 16 + sub) * PPIT + quad * 8];
            f16x4 p01 = *(const f16x4*)&QP[(w * 16 + sub) * PPIT + quad * 8 + 4];
            f16x4 p10 = *(const f16x4*)&QP[(w * 16 + sub) * PPIT + 32 + quad * 8];
            f16x4 p11 = *(const f16x4*)&QP[(w * 16 + sub) * PPIT + 32 + quad * 8 + 4];
            f16x8 pf0 = {p00[0], p00[1], p00[2], p00[3], p01[0], p01[1], p01[2], p01[3]};
            f16x8 pf1 = {p10[0], p10[1], p10[2], p10[3], p11[0], p11[1], p11[2], p11[3]};
            l_acc = __builtin_amdgcn_mfma_f32_16x16x32_f16(pf0, ones, l_acc, 0, 0, 0);
            l_acc = __builtin_amdgcn_mfma_f32_16x16x32_f16(pf1, ones, l_acc, 0, 0, 0);
#pragma unroll
            for (int dt = 0; dt < 4; ++dt) {
                f16x8 vf0 = *(const f16x8*)&Vt[(dt * 16 + sub) * VP + hf * 64 + quad * 8];
                f16x8 vf1 = *(const f16x8*)&Vt[(dt * 16 + sub) * VP + hf * 64 + 32 + quad * 8];
                o[dt] = __builtin_amdgcn_mfma_f32_16x16x32_f16(pf0, vf0, o[dt], 0, 0, 0);
                o[dt] = __builtin_amdgcn_mfma_f32_16x16x32_f16(pf1, vf1, o[dt], 0, 0, 0);
            }
        }

        if (c + 1 < NITER) {   // restage K/V for next chunk
            __syncthreads();   // all reads of current chunk done
            f16* kd = &Ks[krow * KP + kcb];
            *(f16x8*)(kd + 0)  = kr0;
            *(f16x8*)(kd + 8)  = kr1;
            *(f16x8*)(kd + 16) = kr2;
            *(f16x8*)(kd + 24) = kr3;
#pragma unroll
            for (int j = 0; j < 8; ++j) {
                *(f16x2*)&Vt[(w * 16 + j) * VP + 2 * lane]     = (f16x2){vr0[j], vr2[j]};
                *(f16x2*)&Vt[(w * 16 + 8 + j) * VP + 2 * lane] = (f16x2){vr1[j], vr3[j]};
            }
            __syncthreads();
        }
    }
    // epilogue
    float lsc = lscale[h];
#pragma unroll
    for (int r = 0; r < 4; ++r) {
        float inv = lsc / l_acc[r];
        int q = qb + w * 16 + quad * 4 + r;
#pragma unroll
        for (int dt = 0; dt < 4; ++dt)
            Og[((size_t)n * SEQ + q) * CH + h * 64 + dt * 16 + sub] =
                (f16)(o[dt][r] * inv);
    }
}

// ---------------------------------------------------------------------------
// Output projection: A (f16, from attn) direct; W2 fp32 converted during
// LDS staging. fp32 out.
// ---------------------------------------------------------------------------
__global__ __launch_bounds__(256, 3) void out_gemm(const f16* __restrict__ A,
                                                   const float* __restrict__ W,
                                                   const float* __restrict__ bias,
                                                   float* __restrict__ out)
{
    __shared__ f16 As[128 * GP];
    __shared__ f16 Bs[128 * GP];
    const int t    = threadIdx.x;
    const int w    = t >> 6;
    const int lane = t & 63;
    const int quad = lane >> 4;
    const int sub  = lane & 15;
    const int wm   = w & 1, wn = w >> 1;
    const int f0   = blockIdx.x * 128;
    const int m0   = blockIdx.y * 128;
    const int srow = t >> 1;
    const int sk   = (t & 1) * 16;

    const f16*   ag = A + (size_t)(m0 + srow) * CH + sk;
    const float* bg = W + (size_t)(f0 + srow) * CH + sk;
    f16x8 a0 = *(const f16x8*)(ag);
    f16x8 a1 = *(const f16x8*)(ag + 8);
    float4 b4[4];
#pragma unroll
    for (int j = 0; j < 4; ++j) b4[j] = *(const float4*)(bg + 4 * j);

    f32x4 acc[4][4];
#pragma unroll
    for (int i = 0; i < 4; ++i)
#pragma unroll
        for (int j = 0; j < 4; ++j) acc[i][j] = (f32x4){0.f, 0.f, 0.f, 0.f};

    for (int k0 = 0; k0 < CH; k0 += 32) {
        __syncthreads();
        *(f16x8*)&As[srow * GP + sk + 0] = a0;
        *(f16x8*)&As[srow * GP + sk + 8] = a1;
#pragma unroll
        for (int j = 0; j < 4; ++j) {
            f16x4 bv = {(f16)b4[j].x, (f16)b4[j].y, (f16)b4[j].z, (f16)b4[j].w};
            *(f16x4*)&Bs[srow * GP + sk + 4 * j] = bv;
        }
        __syncthreads();
        if (k0 + 32 < CH) {
            a0 = *(const f16x8*)(ag + k0 + 32);
            a1 = *(const f16x8*)(ag + k0 + 40);
#pragma unroll
            for (int j = 0; j < 4; ++j)
                b4[j] = *(const float4*)(bg + k0 + 32 + 4 * j);
        }
        f16x8 af[4], bf[4];
#pragma unroll
        for (int i = 0; i < 4; ++i) {
            af[i] = *(const f16x8*)&As[(wm * 64 + i * 16 + sub) * GP + quad * 8];
            bf[i] = *(const f16x8*)&Bs[(wn * 64 + i * 16 + sub) * GP + quad * 8];
        }
#pragma unroll
        for (int i = 0; i < 4; ++i)
#pragma unroll
            for (int j = 0; j < 4; ++j)
                acc[i][j] = __builtin_amdgcn_mfma_f32_16x16x32_f16(af[i], bf[j], acc[i][j], 0, 0, 0);
    }
    float bb[4];
#pragma unroll
    for (int j = 0; j < 4; ++j) bb[j] = bias[f0 + wn * 64 + j * 16 + sub];
#pragma unroll
    for (int i = 0; i < 4; ++i)
#pragma unroll
        for (int r = 0; r < 4; ++r) {
            int m = m0 + wm * 64 + i * 16 + quad * 4 + r;
            float* orow = out + (size_t)m * CH + f0 + wn * 64;
#pragma unroll
            for (int j = 0; j < 4; ++j)
                orow[j * 16 + sub] = acc[i][j][r] + bb[j];
        }
}

extern "C" void kernel_launch(void* const* d_in, const int* in_sizes, int n_in,
                              void* d_out, int out_size, void* d_ws, size_t ws_size,
                              hipStream_t stream) {
    const float* x    = (const float*)d_in[0];
    const float* w1   = (const float*)d_in[1];
    const float* b1   = (const float*)d_in[2];
    const float* ls   = (const float*)d_in[3];
    const float* lrn  = (const float*)d_in[4];
    const float* w2   = (const float*)d_in[5];
    const float* b2   = (const float*)d_in[6];
    const float* msk  = (const float*)d_in[7];
    f16*   ws16 = (f16*)d_ws;
    int*   flag = (int*)(ws16 + FLAGO);
    float* out  = (float*)d_out;

    (void)hipMemsetAsync(flag, 0, 4, stream);
    hipLaunchKernelGGL(mask_scan, dim3(4096), dim3(256), 0, stream, msk, flag);
    hipLaunchKernelGGL(qkv_gemm, dim3(F3 / 128, (NB * SEQ) / 128), dim3(256), 0, stream,
                       x, w1, b1, ls, ws16);
    hipLaunchKernelGGL(attn, dim3(SEQ / 64, NH, NB), dim3(256), 0, stream,
                       ws16, ws16 + QSZ, ws16 + 2 * QSZ, msk, lrn, flag,
                       ws16 + OATT);
    hipLaunchKernelGGL(out_gemm, dim3(CH / 128, (NB * SEQ) / 128), dim3(256), 0, stream,
                       ws16 + OATT, w2, b2, out);
}

// Round 11
// 214.078 us; speedup vs baseline: 1.2863x; 1.1267x over previous
//
#include <hip/hip_runtime.h>
#include <math.h>

// Problem constants
#define NB   2
#define SEQ  2048
#define CH   768
#define NH   12
#define HD   64
#define F3   2304
#define LSMAX 4.605170185988092f
#define LOG2E 1.4426950408889634f

typedef _Float16 f16;
typedef __attribute__((ext_vector_type(8))) _Float16 f16x8;
typedef __attribute__((ext_vector_type(4))) _Float16 f16x4;
typedef __attribute__((ext_vector_type(2))) _Float16 f16x2;
typedef __attribute__((ext_vector_type(4))) float f32x4;

// f16 workspace layout (units: f16 elements)
#define QSZ   3145728                 // per Q/K/V tensor
#define OATT  (3 * QSZ)               // attn out [N,L,C] f16 (3145728)
#define XHOFF 12582912                // x -> f16 (3145728)
#define W1OFF 15728640                // in_proj_w -> f16 (1769472)
#define W2OFF 17498112                // out_proj_w -> f16 (589824)
#define FLAGO 18087936                // int flag: mask nonzero

// LDS pitches
#define KP   72    // attn K tile: 144B rows, 16B-aligned b128
#define VP   136   // attn Vt tile (128 keys): 272B rows, 16B-aligned b128
#define PPIT 76    // attn Q/P tile: 152B rows, b64 frag reads
#define GP2  72    // GEMM BK=64 tiles: 144B rows, 16B-aligned b128

// ---------------------------------------------------------------------------
// fp32 -> f16 convert of X, W1, W2 (one-time; GEMMs re-read these many times,
// so converting once beats fused conversion — measured R10). Mask: flag scan.
// ---------------------------------------------------------------------------
__global__ __launch_bounds__(256) void cvt_f16(const float* __restrict__ X,
                                               const float* __restrict__ W1,
                                               const float* __restrict__ W2,
                                               const float* __restrict__ M,
                                               f16* __restrict__ Xh,
                                               f16* __restrict__ W1h,
                                               f16* __restrict__ W2h,
                                               int* __restrict__ flag)
{
    int tid = blockIdx.x * 256 + threadIdx.x;
    if (blockIdx.y == 3) {   // mask: flag-only scan
        if (tid < 1048576) {
            float4 v = ((const float4*)M)[tid];
            bool nz = (v.x != 0.f) || (v.y != 0.f) || (v.z != 0.f) || (v.w != 0.f);
            if (__any(nz) && (threadIdx.x & 63) == 0) atomicOr(flag, 1);
        }
        return;
    }
    const float* src; f16* dst; int n4;
    switch (blockIdx.y) {
        case 0:  src = X;  dst = Xh;  n4 = 786432;  break;
        case 1:  src = W1; dst = W1h; n4 = 442368;  break;
        default: src = W2; dst = W2h; n4 = 147456;  break;
    }
    if (tid < n4) {
        float4 v = ((const float4*)src)[tid];
        f16x4 o = {(f16)v.x, (f16)v.y, (f16)v.z, (f16)v.w};
        ((f16x4*)dst)[tid] = o;
    }
}

// ---------------------------------------------------------------------------
// QKV GEMM, f16 inputs, BK=64 (half the barrier count of BK=32 — these
// blocks have ~2.25/CU co-residency so every barrier drain is exposed),
// reg-prefetched staging. 128x128 tile, 4 waves 2x2. Epilogue: bias,
// l2-norm Q/K rows, fold exp(min(ls,MAX))*LOG2E into Q.
// ---------------------------------------------------------------------------
__global__ __launch_bounds__(256, 3) void qkv_gemm(const f16* __restrict__ Xh,
                                                   const f16* __restrict__ Wh,
                                                   const float* __restrict__ bias,
                                                   const float* __restrict__ logit_scale,
                                                   f16* __restrict__ qkv16)
{
    __shared__ f16 As[128 * GP2];
    __shared__ f16 Bs[128 * GP2];
    const int t    = threadIdx.x;
    const int w    = t >> 6;
    const int lane = t & 63;
    const int quad = lane >> 4;
    const int sub  = lane & 15;
    const int wm   = w & 1, wn = w >> 1;
    const int f0   = blockIdx.x * 128;
    const int m0   = blockIdx.y * 128;
    const int srow = t >> 1;            // 0..127
    const int sk   = (t & 1) * 32;      // 0 / 32

    const f16* ag = Xh + (size_t)(m0 + srow) * CH + sk;
    const f16* bg = Wh + (size_t)(f0 + srow) * CH + sk;
    f16x8 a[4], b[4];
#pragma unroll
    for (int j = 0; j < 4; ++j) {
        a[j] = *(const f16x8*)(ag + 8 * j);
        b[j] = *(const f16x8*)(bg + 8 * j);
    }

    f32x4 acc[4][4];
#pragma unroll
    for (int i = 0; i < 4; ++i)
#pragma unroll
        for (int j = 0; j < 4; ++j) acc[i][j] = (f32x4){0.f, 0.f, 0.f, 0.f};

    for (int k0 = 0; k0 < CH; k0 += 64) {
        __syncthreads();
#pragma unroll
        for (int j = 0; j < 4; ++j) {
            *(f16x8*)&As[srow * GP2 + sk + 8 * j] = a[j];
            *(f16x8*)&Bs[srow * GP2 + sk + 8 * j] = b[j];
        }
        __syncthreads();
        if (k0 + 64 < CH) {
#pragma unroll
            for (int j = 0; j < 4; ++j) {
                a[j] = *(const f16x8*)(ag + k0 + 64 + 8 * j);
                b[j] = *(const f16x8*)(bg + k0 + 64 + 8 * j);
            }
        }
#pragma unroll
        for (int kk = 0; kk < 64; kk += 32) {
            f16x8 af[4], bf[4];
#pragma unroll
            for (int i = 0; i < 4; ++i) {
                af[i] = *(const f16x8*)&As[(wm * 64 + i * 16 + sub) * GP2 + kk + quad * 8];
                bf[i] = *(const f16x8*)&Bs[(wn * 64 + i * 16 + sub) * GP2 + kk + quad * 8];
            }
#pragma unroll
            for (int i = 0; i < 4; ++i)
#pragma unroll
                for (int j = 0; j < 4; ++j)
                    acc[i][j] = __builtin_amdgcn_mfma_f32_16x16x32_f16(af[i], bf[j], acc[i][j], 0, 0, 0);
        }
    }

    const int t3 = f0 / CH;                       // 0=q,1=k,2=v (block-uniform)
    const int h  = ((f0 + wn * 64) % CH) >> 6;    // wave-uniform head
    f16* dst = qkv16 + (size_t)t3 * QSZ;
    float lsv = (t3 == 0) ? __expf(fminf(logit_scale[h], LSMAX)) * LOG2E : 1.0f;
    float bb[4];
#pragma unroll
    for (int j = 0; j < 4; ++j) bb[j] = bias[f0 + wn * 64 + j * 16 + sub];
#pragma unroll
    for (int i = 0; i < 4; ++i) {
#pragma unroll
        for (int r = 0; r < 4; ++r) {
            int m = m0 + wm * 64 + i * 16 + quad * 4 + r;
            int n = m >> 11, l = m & 2047;
            float v[4];
#pragma unroll
            for (int j = 0; j < 4; ++j) v[j] = acc[i][j][r] + bb[j];
            float scale = 1.0f;
            if (t3 < 2) {
                float ss = v[0] * v[0] + v[1] * v[1] + v[2] * v[2] + v[3] * v[3];
#pragma unroll
                for (int mk = 1; mk < 16; mk <<= 1) ss += __shfl_xor(ss, mk, 64);
                scale = 1.0f / fmaxf(sqrtf(ss), 1e-12f);
                if (t3 == 0) scale *= lsv;
            }
            f16* drow = dst + (((size_t)n * NH + h) * SEQ + l) * HD;
#pragma unroll
            for (int j = 0; j < 4; ++j)
                drow[j * 16 + sub] = (f16)(v[j] * scale);
        }
    }
}

// ---------------------------------------------------------------------------
// Flash attention (R7 winner, verbatim): f16 MFMA, KC=128 keys/iteration,
// log2-domain softmax, single-buffer K/V LDS + full register prefetch,
// P in two 64-key halves through one shared Q/P tile, l via ones-MFMA.
// ---------------------------------------------------------------------------
__global__ __launch_bounds__(256, 3) void attn(const f16* __restrict__ Qh,
                                               const f16* __restrict__ Kh,
                                               const f16* __restrict__ Vh,
                                               const float* __restrict__ M32,
                                               const float* __restrict__ lscale,
                                               const int* __restrict__ flag,
                                               f16* __restrict__ Og)
{
    __shared__ f16 Ks[128 * KP];    // [key][d]          18.4 KB
    __shared__ f16 Vt[64 * VP];     // [d][key 0..127]   17.4 KB
    __shared__ f16 QP[64 * PPIT];   // Q tile -> P tile   9.7 KB

    const int t    = threadIdx.x;
    const int w    = t >> 6;
    const int lane = t & 63;
    const int quad = lane >> 4;
    const int sub  = lane & 15;
    const int qb   = blockIdx.x * 64;
    const int h    = blockIdx.y, n = blockIdx.z;
    const bool has_mask = (*flag) != 0;

    const f16* Qg = Qh + ((size_t)(n * NH + h) * SEQ + qb) * HD;
    const f16* Kg = Kh + (size_t)(n * NH + h) * SEQ * HD;
    const f16* Vg = Vh + (size_t)(n * NH + h) * SEQ * HD;
    const float* Mg = M32 + (size_t)(qb + w * 16 + quad * 4) * SEQ;

    // stage Q
#pragma unroll
    for (int rep = 0; rep < 2; ++rep) {
        int id = rep * 256 + t;
        int row = id >> 3, c8 = id & 7;
        f16x8 v = *(const f16x8*)&Qg[row * 64 + c8 * 8];
        *(f16x4*)&QP[row * PPIT + c8 * 8 + 0] = (f16x4){v[0], v[1], v[2], v[3]};
        *(f16x4*)&QP[row * PPIT + c8 * 8 + 4] = (f16x4){v[4], v[5], v[6], v[7]};
    }

    // prefetch chunk 0: K 4 b128 (row t>>1, colblock (t&1)*32),
    //                   V 4 b128 (keys 2*lane, 2*lane+1; d-slice w*16..+16)
    const int krow = t >> 1;
    const int kcb  = (t & 1) * 32;
    f16x8 kr0, kr1, kr2, kr3, vr0, vr1, vr2, vr3;
    {
        const f16* kp = Kg + krow * 64 + kcb;
        kr0 = *(const f16x8*)(kp + 0);
        kr1 = *(const f16x8*)(kp + 8);
        kr2 = *(const f16x8*)(kp + 16);
        kr3 = *(const f16x8*)(kp + 24);
        const f16* vp = Vg + (2 * lane) * 64 + w * 16;
        vr0 = *(const f16x8*)(vp + 0);
        vr1 = *(const f16x8*)(vp + 8);
        vr2 = *(const f16x8*)(vp + 64);
        vr3 = *(const f16x8*)(vp + 72);
    }

    __syncthreads();   // Q staged
    f16x8 qf0, qf1;
    {
        f16x4 l0 = *(const f16x4*)&QP[(w * 16 + sub) * PPIT + quad * 8];
        f16x4 l1 = *(const f16x4*)&QP[(w * 16 + sub) * PPIT + quad * 8 + 4];
        f16x4 l2 = *(const f16x4*)&QP[(w * 16 + sub) * PPIT + 32 + quad * 8];
        f16x4 l3 = *(const f16x4*)&QP[(w * 16 + sub) * PPIT + 32 + quad * 8 + 4];
        qf0 = (f16x8){l0[0], l0[1], l0[2], l0[3], l1[0], l1[1], l1[2], l1[3]};
        qf1 = (f16x8){l2[0], l2[1], l2[2], l2[3], l3[0], l3[1], l3[2], l3[3]};
    }

    // store chunk 0 into LDS
    {
        f16* kd = &Ks[krow * KP + kcb];
        *(f16x8*)(kd + 0)  = kr0;
        *(f16x8*)(kd + 8)  = kr1;
        *(f16x8*)(kd + 16) = kr2;
        *(f16x8*)(kd + 24) = kr3;
#pragma unroll
        for (int j = 0; j < 8; ++j) {
            *(f16x2*)&Vt[(w * 16 + j) * VP + 2 * lane]     = (f16x2){vr0[j], vr2[j]};
            *(f16x2*)&Vt[(w * 16 + 8 + j) * VP + 2 * lane] = (f16x2){vr1[j], vr3[j]};
        }
    }
    __syncthreads();

    const f16x8 ones = {(f16)1.f, (f16)1.f, (f16)1.f, (f16)1.f,
                        (f16)1.f, (f16)1.f, (f16)1.f, (f16)1.f};
    f32x4 o[4];
    f32x4 l_acc = (f32x4){0.f, 0.f, 0.f, 0.f};
    float m_run[4];
#pragma unroll
    for (int dt = 0; dt < 4; ++dt) o[dt] = (f32x4){0.f, 0.f, 0.f, 0.f};
#pragma unroll
    for (int r = 0; r < 4; ++r) m_run[r] = -1e30f;

    const int NITER = SEQ / 128;
    for (int c = 0; c < NITER; ++c) {
        const int c0 = c * 128;
        // prefetch next chunk (fully overlapped with compute below)
        if (c + 1 < NITER) {
            const f16* kp = Kg + (c0 + 128 + krow) * 64 + kcb;
            kr0 = *(const f16x8*)(kp + 0);
            kr1 = *(const f16x8*)(kp + 8);
            kr2 = *(const f16x8*)(kp + 16);
            kr3 = *(const f16x8*)(kp + 24);
            const f16* vp = Vg + (c0 + 128 + 2 * lane) * 64 + w * 16;
            vr0 = *(const f16x8*)(vp + 0);
            vr1 = *(const f16x8*)(vp + 8);
            vr2 = *(const f16x8*)(vp + 64);
            vr3 = *(const f16x8*)(vp + 72);
        }

        // S = Q.K^T over 128 keys (8 column tiles)
        f32x4 s[8];
#pragma unroll
        for (int ct = 0; ct < 8; ++ct) {
            f16x8 kf0 = *(const f16x8*)&Ks[(ct * 16 + sub) * KP + quad * 8];
            f16x8 kf1 = *(const f16x8*)&Ks[(ct * 16 + sub) * KP + 32 + quad * 8];
            f32x4 a = (f32x4){0.f, 0.f, 0.f, 0.f};
            a = __builtin_amdgcn_mfma_f32_16x16x32_f16(qf0, kf0, a, 0, 0, 0);
            a = __builtin_amdgcn_mfma_f32_16x16x32_f16(qf1, kf1, a, 0, 0, 0);
            s[ct] = a;
        }
        if (has_mask) {   // rare path: fp32 mask direct, scaled to log2 domain
#pragma unroll
            for (int ct = 0; ct < 8; ++ct)
#pragma unroll
                for (int r = 0; r < 4; ++r)
                    s[ct][r] += LOG2E * Mg[(size_t)r * SEQ + c0 + ct * 16 + sub];
        }
        // row max over 128 cols + running, packed-f16 16-lane butterfly
        float mnew[4];
#pragma unroll
        for (int r = 0; r < 4; ++r) {
            float a01 = fmaxf(s[0][r], s[1][r]), a23 = fmaxf(s[2][r], s[3][r]);
            float a45 = fmaxf(s[4][r], s[5][r]), a67 = fmaxf(s[6][r], s[7][r]);
            mnew[r] = fmaxf(fmaxf(fmaxf(a01, a23), fmaxf(a45, a67)), m_run[r]);
        }
        {
            union { f16x2 h; int i; } p0, p1, v0, v1;
            p0.h = (f16x2){(f16)mnew[0], (f16)mnew[1]};
            p1.h = (f16x2){(f16)mnew[2], (f16)mnew[3]};
#pragma unroll
            for (int mk = 1; mk < 16; mk <<= 1) {
                v0.i = __shfl_xor(p0.i, mk, 64);
                v1.i = __shfl_xor(p1.i, mk, 64);
                p0.h = __builtin_elementwise_max(p0.h, v0.h);
                p1.h = __builtin_elementwise_max(p1.h, v1.h);
            }
            mnew[0] = (float)p0.h[0]; mnew[1] = (float)p0.h[1];
            mnew[2] = (float)p1.h[0]; mnew[3] = (float)p1.h[1];
        }
        float alpha[4];
#pragma unroll
        for (int r = 0; r < 4; ++r) {
            alpha[r] = exp2f(m_run[r] - mnew[r]);
            m_run[r] = mnew[r];
        }
        // rescale O and l
#pragma unroll
        for (int dt = 0; dt < 4; ++dt)
#pragma unroll
            for (int r = 0; r < 4; ++r) o[dt][r] *= alpha[r];
#pragma unroll
        for (int r = 0; r < 4; ++r) l_acc[r] *= alpha[r];

        // two 64-key halves through the shared P tile (wave-private rows)
#pragma unroll
        for (int hf = 0; hf < 2; ++hf) {
#pragma unroll
            for (int ct = 0; ct < 4; ++ct)
#pragma unroll
                for (int r = 0; r < 4; ++r) {
                    float p = exp2f(s[hf * 4 + ct][r] - mnew[r]);
                    QP[(w * 16 + quad * 4 + r) * PPIT + ct * 16 + sub] = (f16)p;
                }
            f16x4 p00 = *(const f16x4*)&QP[(w * 16 + sub) * PPIT + quad * 8];
            f16x4 p01 = *(const f16x4*)&QP[(w * 16 + sub) * PPIT + quad * 8 + 4];
            f16x4 p10 = *(const f16x4*)&QP[(w * 16 + sub) * PPIT + 32 + quad * 8];
            f16x4 p11 = *(const f16x4*)&QP[(w * 16 + sub) * PPIT + 32 + quad * 8 + 4];
            f16x8 pf0 = {p00[0], p00[1], p00[2], p00[3], p01[0], p01[1], p01[2], p01[3]};
            f16x8 pf1 = {p10[0], p10[1], p10[2], p10[3], p11[0], p11[1], p11[2], p11[3]};
            l_acc = __builtin_amdgcn_mfma_f32_16x16x32_f16(pf0, ones, l_acc, 0, 0, 0);
            l_acc = __builtin_amdgcn_mfma_f32_16x16x32_f16(pf1, ones, l_acc, 0, 0, 0);
#pragma unroll
            for (int dt = 0; dt < 4; ++dt) {
                f16x8 vf0 = *(const f16x8*)&Vt[(dt * 16 + sub) * VP + hf * 64 + quad * 8];
                f16x8 vf1 = *(const f16x8*)&Vt[(dt * 16 + sub) * VP + hf * 64 + 32 + quad * 8];
                o[dt] = __builtin_amdgcn_mfma_f32_16x16x32_f16(pf0, vf0, o[dt], 0, 0, 0);
                o[dt] = __builtin_amdgcn_mfma_f32_16x16x32_f16(pf1, vf1, o[dt], 0, 0, 0);
            }
        }

        if (c + 1 < NITER) {   // restage K/V for next chunk
            __syncthreads();   // all reads of current chunk done
            f16* kd = &Ks[krow * KP + kcb];
            *(f16x8*)(kd + 0)  = kr0;
            *(f16x8*)(kd + 8)  = kr1;
            *(f16x8*)(kd + 16) = kr2;
            *(f16x8*)(kd + 24) = kr3;
#pragma unroll
            for (int j = 0; j < 8; ++j) {
                *(f16x2*)&Vt[(w * 16 + j) * VP + 2 * lane]     = (f16x2){vr0[j], vr2[j]};
                *(f16x2*)&Vt[(w * 16 + 8 + j) * VP + 2 * lane] = (f16x2){vr1[j], vr3[j]};
            }
            __syncthreads();
        }
    }
    // epilogue
    float lsc = lscale[h];
#pragma unroll
    for (int r = 0; r < 4; ++r) {
        float inv = lsc / l_acc[r];
        int q = qb + w * 16 + quad * 4 + r;
#pragma unroll
        for (int dt = 0; dt < 4; ++dt)
            Og[((size_t)n * SEQ + q) * CH + h * 64 + dt * 16 + sub] =
                (f16)(o[dt][r] * inv);
    }
}

// ---------------------------------------------------------------------------
// Output projection, f16 inputs, BK=64, reg-prefetched staging. fp32 out.
// ---------------------------------------------------------------------------
__global__ __launch_bounds__(256, 3) void out_gemm(const f16* __restrict__ A,
                                                   const f16* __restrict__ Wh,
                                                   const float* __restrict__ bias,
                                                   float* __restrict__ out)
{
    __shared__ f16 As[128 * GP2];
    __shared__ f16 Bs[128 * GP2];
    const int t    = threadIdx.x;
    const int w    = t >> 6;
    const int lane = t & 63;
    const int quad = lane >> 4;
    const int sub  = lane & 15;
    const int wm   = w & 1, wn = w >> 1;
    const int f0   = blockIdx.x * 128;
    const int m0   = blockIdx.y * 128;
    const int srow = t >> 1;
    const int sk   = (t & 1) * 32;

    const f16* ag = A + (size_t)(m0 + srow) * CH + sk;
    const f16* bg = Wh + (size_t)(f0 + srow) * CH + sk;
    f16x8 a[4], b[4];
#pragma unroll
    for (int j = 0; j < 4; ++j) {
        a[j] = *(const f16x8*)(ag + 8 * j);
        b[j] = *(const f16x8*)(bg + 8 * j);
    }

    f32x4 acc[4][4];
#pragma unroll
    for (int i = 0; i < 4; ++i)
#pragma unroll
        for (int j = 0; j < 4; ++j) acc[i][j] = (f32x4){0.f, 0.f, 0.f, 0.f};

    for (int k0 = 0; k0 < CH; k0 += 64) {
        __syncthreads();
#pragma unroll
        for (int j = 0; j < 4; ++j) {
            *(f16x8*)&As[srow * GP2 + sk + 8 * j] = a[j];
            *(f16x8*)&Bs[srow * GP2 + sk + 8 * j] = b[j];
        }
        __syncthreads();
        if (k0 + 64 < CH) {
#pragma unroll
            for (int j = 0; j < 4; ++j) {
                a[j] = *(const f16x8*)(ag + k0 + 64 + 8 * j);
                b[j] = *(const f16x8*)(bg + k0 + 64 + 8 * j);
            }
        }
#pragma unroll
        for (int kk = 0; kk < 64; kk += 32) {
            f16x8 af[4], bf[4];
#pragma unroll
            for (int i = 0; i < 4; ++i) {
                af[i] = *(const f16x8*)&As[(wm * 64 + i * 16 + sub) * GP2 + kk + quad * 8];
                bf[i] = *(const f16x8*)&Bs[(wn * 64 + i * 16 + sub) * GP2 + kk + quad * 8];
            }
#pragma unroll
            for (int i = 0; i < 4; ++i)
#pragma unroll
                for (int j = 0; j < 4; ++j)
                    acc[i][j] = __builtin_amdgcn_mfma_f32_16x16x32_f16(af[i], bf[j], acc[i][j], 0, 0, 0);
        }
    }
    float bb[4];
#pragma unroll
    for (int j = 0; j < 4; ++j) bb[j] = bias[f0 + wn * 64 + j * 16 + sub];
#pragma unroll
    for (int i = 0; i < 4; ++i)
#pragma unroll
        for (int r = 0; r < 4; ++r) {
            int m = m0 + wm * 64 + i * 16 + quad * 4 + r;
            float* orow = out + (size_t)m * CH + f0 + wn * 64;
#pragma unroll
            for (int j = 0; j < 4; ++j)
                orow[j * 16 + sub] = acc[i][j][r] + bb[j];
        }
}

extern "C" void kernel_launch(void* const* d_in, const int* in_sizes, int n_in,
                              void* d_out, int out_size, void* d_ws, size_t ws_size,
                              hipStream_t stream) {
    const float* x    = (const float*)d_in[0];
    const float* w1   = (const float*)d_in[1];
    const float* b1   = (const float*)d_in[2];
    const float* ls   = (const float*)d_in[3];
    const float* lrn  = (const float*)d_in[4];
    const float* w2   = (const float*)d_in[5];
    const float* b2   = (const float*)d_in[6];
    const float* msk  = (const float*)d_in[7];
    f16*   ws16 = (f16*)d_ws;
    int*   flag = (int*)(ws16 + FLAGO);
    float* out  = (float*)d_out;

    (void)hipMemsetAsync(flag, 0, 4, stream);
    hipLaunchKernelGGL(cvt_f16, dim3(4096, 4), dim3(256), 0, stream,
                       x, w1, w2, msk,
                       ws16 + XHOFF, ws16 + W1OFF, ws16 + W2OFF, flag);
    hipLaunchKernelGGL(qkv_gemm, dim3(F3 / 128, (NB * SEQ) / 128), dim3(256), 0, stream,
                       ws16 + XHOFF, ws16 + W1OFF, b1, ls, ws16);
    hipLaunchKernelGGL(attn, dim3(SEQ / 64, NH, NB), dim3(256), 0, stream,
                       ws16, ws16 + QSZ, ws16 + 2 * QSZ, msk, lrn, flag,
                       ws16 + OATT);
    hipLaunchKernelGGL(out_gemm, dim3(CH / 128, (NB * SEQ) / 128), dim3(256), 0, stream,
                       ws16 + OATT, ws16 + W2OFF, b2, out);
}

// Round 12
// 209.607 us; speedup vs baseline: 1.3137x; 1.0213x over previous
//
#include <hip/hip_runtime.h>
#include <math.h>

// Problem constants
#define NB   2
#define SEQ  2048
#define CH   768
#define NH   12
#define HD   64
#define F3   2304
#define LSMAX 4.605170185988092f
#define LOG2E 1.4426950408889634f

typedef _Float16 f16;
typedef __attribute__((ext_vector_type(8))) _Float16 f16x8;
typedef __attribute__((ext_vector_type(4))) _Float16 f16x4;
typedef __attribute__((ext_vector_type(2))) _Float16 f16x2;
typedef __attribute__((ext_vector_type(4))) float f32x4;

// f16 workspace layout (units: f16 elements)
#define QSZ   3145728                 // per Q/K/V tensor
#define OATT  (3 * QSZ)               // attn out [N,L,C] f16 (3145728)
#define XHOFF 12582912                // x -> f16 (3145728)
#define W1OFF 15728640                // in_proj_w -> f16 (1769472)
#define W2OFF 17498112                // out_proj_w -> f16 (589824)
#define FLAGO 18087936                // int flag: mask nonzero

// LDS pitches
#define KP   72    // attn K tile: 144B rows, 16B-aligned b128
#define VP   136   // attn Vt tile (128 keys): 272B rows, 16B-aligned b128
#define PPIT 76    // attn Q/P tile: 152B rows, b64 frag reads
#define GP   40    // GEMM BK=32 tiles: 80B rows, 16B-aligned b128
#define GP2  72    // out GEMM BK=64 tile: 144B rows, 16B-aligned b128

// ---------------------------------------------------------------------------
// fp32 -> f16 convert of X, W1, W2 (one-time; GEMMs re-read these many times,
// so converting once beats fused conversion — measured R10). Mask: flag scan.
// ---------------------------------------------------------------------------
__global__ __launch_bounds__(256) void cvt_f16(const float* __restrict__ X,
                                               const float* __restrict__ W1,
                                               const float* __restrict__ W2,
                                               const float* __restrict__ M,
                                               f16* __restrict__ Xh,
                                               f16* __restrict__ W1h,
                                               f16* __restrict__ W2h,
                                               int* __restrict__ flag)
{
    int tid = blockIdx.x * 256 + threadIdx.x;
    if (blockIdx.y == 3) {   // mask: flag-only scan
        if (tid < 1048576) {
            float4 v = ((const float4*)M)[tid];
            bool nz = (v.x != 0.f) || (v.y != 0.f) || (v.z != 0.f) || (v.w != 0.f);
            if (__any(nz) && (threadIdx.x & 63) == 0) atomicOr(flag, 1);
        }
        return;
    }
    const float* src; f16* dst; int n4;
    switch (blockIdx.y) {
        case 0:  src = X;  dst = Xh;  n4 = 786432;  break;
        case 1:  src = W1; dst = W1h; n4 = 442368;  break;
        default: src = W2; dst = W2h; n4 = 147456;  break;
    }
    if (tid < n4) {
        float4 v = ((const float4*)src)[tid];
        f16x4 o = {(f16)v.x, (f16)v.y, (f16)v.z, (f16)v.w};
        ((f16x4*)dst)[tid] = o;
    }
}

// ---------------------------------------------------------------------------
// QKV GEMM (R7 structure: BK=32, reg-prefetch), launch_bounds(256,4) so all
// 576 blocks are co-resident (4 blocks/CU capacity; LDS 20.5KB). 128x128
// tile, 4 waves 2x2. Epilogue: bias, l2-norm Q/K rows, fold
// exp(min(ls,MAX))*LOG2E into Q.
// ---------------------------------------------------------------------------
__global__ __launch_bounds__(256, 4) void qkv_gemm(const f16* __restrict__ Xh,
                                                   const f16* __restrict__ Wh,
                                                   const float* __restrict__ bias,
                                                   const float* __restrict__ logit_scale,
                                                   f16* __restrict__ qkv16)
{
    __shared__ f16 As[128 * GP];
    __shared__ f16 Bs[128 * GP];
    const int t    = threadIdx.x;
    const int w    = t >> 6;
    const int lane = t & 63;
    const int quad = lane >> 4;
    const int sub  = lane & 15;
    const int wm   = w & 1, wn = w >> 1;
    const int f0   = blockIdx.x * 128;
    const int m0   = blockIdx.y * 128;
    const int srow = t >> 1;
    const int sk   = (t & 1) * 16;

    const f16* ag = Xh + (size_t)(m0 + srow) * CH + sk;
    const f16* bg = Wh + (size_t)(f0 + srow) * CH + sk;
    f16x8 a0 = *(const f16x8*)(ag);
    f16x8 a1 = *(const f16x8*)(ag + 8);
    f16x8 b0 = *(const f16x8*)(bg);
    f16x8 b1 = *(const f16x8*)(bg + 8);

    f32x4 acc[4][4];
#pragma unroll
    for (int i = 0; i < 4; ++i)
#pragma unroll
        for (int j = 0; j < 4; ++j) acc[i][j] = (f32x4){0.f, 0.f, 0.f, 0.f};

    for (int k0 = 0; k0 < CH; k0 += 32) {
        __syncthreads();
        *(f16x8*)&As[srow * GP + sk + 0] = a0;
        *(f16x8*)&As[srow * GP + sk + 8] = a1;
        *(f16x8*)&Bs[srow * GP + sk + 0] = b0;
        *(f16x8*)&Bs[srow * GP + sk + 8] = b1;
        __syncthreads();
        if (k0 + 32 < CH) {
            a0 = *(const f16x8*)(ag + k0 + 32);
            a1 = *(const f16x8*)(ag + k0 + 40);
            b0 = *(const f16x8*)(bg + k0 + 32);
            b1 = *(const f16x8*)(bg + k0 + 40);
        }
        f16x8 af[4], bf[4];
#pragma unroll
        for (int i = 0; i < 4; ++i) {
            af[i] = *(const f16x8*)&As[(wm * 64 + i * 16 + sub) * GP + quad * 8];
            bf[i] = *(const f16x8*)&Bs[(wn * 64 + i * 16 + sub) * GP + quad * 8];
        }
#pragma unroll
        for (int i = 0; i < 4; ++i)
#pragma unroll
            for (int j = 0; j < 4; ++j)
                acc[i][j] = __builtin_amdgcn_mfma_f32_16x16x32_f16(af[i], bf[j], acc[i][j], 0, 0, 0);
    }

    const int t3 = f0 / CH;                       // 0=q,1=k,2=v (block-uniform)
    const int h  = ((f0 + wn * 64) % CH) >> 6;    // wave-uniform head
    f16* dst = qkv16 + (size_t)t3 * QSZ;
    float lsv = (t3 == 0) ? __expf(fminf(logit_scale[h], LSMAX)) * LOG2E : 1.0f;
    float bb[4];
#pragma unroll
    for (int j = 0; j < 4; ++j) bb[j] = bias[f0 + wn * 64 + j * 16 + sub];
#pragma unroll
    for (int i = 0; i < 4; ++i) {
#pragma unroll
        for (int r = 0; r < 4; ++r) {
            int m = m0 + wm * 64 + i * 16 + quad * 4 + r;
            int n = m >> 11, l = m & 2047;
            float v[4];
#pragma unroll
            for (int j = 0; j < 4; ++j) v[j] = acc[i][j][r] + bb[j];
            float scale = 1.0f;
            if (t3 < 2) {
                float ss = v[0] * v[0] + v[1] * v[1] + v[2] * v[2] + v[3] * v[3];
#pragma unroll
                for (int mk = 1; mk < 16; mk <<= 1) ss += __shfl_xor(ss, mk, 64);
                scale = 1.0f / fmaxf(sqrtf(ss), 1e-12f);
                if (t3 == 0) scale *= lsv;
            }
            f16* drow = dst + (((size_t)n * NH + h) * SEQ + l) * HD;
#pragma unroll
            for (int j = 0; j < 4; ++j)
                drow[j * 16 + sub] = (f16)(v[j] * scale);
        }
    }
}

// ---------------------------------------------------------------------------
// Flash attention (R7 winner, verbatim): f16 MFMA, KC=128 keys/iteration,
// log2-domain softmax, single-buffer K/V LDS + full register prefetch,
// P in two 64-key halves through one shared Q/P tile, l via ones-MFMA.
// ---------------------------------------------------------------------------
__global__ __launch_bounds__(256, 3) void attn(const f16* __restrict__ Qh,
                                               const f16* __restrict__ Kh,
                                               const f16* __restrict__ Vh,
                                               const float* __restrict__ M32,
                                               const float* __restrict__ lscale,
                                               const int* __restrict__ flag,
                                               f16* __restrict__ Og)
{
    __shared__ f16 Ks[128 * KP];    // [key][d]          18.4 KB
    __shared__ f16 Vt[64 * VP];     // [d][key 0..127]   17.4 KB
    __shared__ f16 QP[64 * PPIT];   // Q tile -> P tile   9.7 KB

    const int t    = threadIdx.x;
    const int w    = t >> 6;
    const int lane = t & 63;
    const int quad = lane >> 4;
    const int sub  = lane & 15;
    const int qb   = blockIdx.x * 64;
    const int h    = blockIdx.y, n = blockIdx.z;
    const bool has_mask = (*flag) != 0;

    const f16* Qg = Qh + ((size_t)(n * NH + h) * SEQ + qb) * HD;
    const f16* Kg = Kh + (size_t)(n * NH + h) * SEQ * HD;
    const f16* Vg = Vh + (size_t)(n * NH + h) * SEQ * HD;
    const float* Mg = M32 + (size_t)(qb + w * 16 + quad * 4) * SEQ;

    // stage Q
#pragma unroll
    for (int rep = 0; rep < 2; ++rep) {
        int id = rep * 256 + t;
        int row = id >> 3, c8 = id & 7;
        f16x8 v = *(const f16x8*)&Qg[row * 64 + c8 * 8];
        *(f16x4*)&QP[row * PPIT + c8 * 8 + 0] = (f16x4){v[0], v[1], v[2], v[3]};
        *(f16x4*)&QP[row * PPIT + c8 * 8 + 4] = (f16x4){v[4], v[5], v[6], v[7]};
    }

    // prefetch chunk 0: K 4 b128 (row t>>1, colblock (t&1)*32),
    //                   V 4 b128 (keys 2*lane, 2*lane+1; d-slice w*16..+16)
    const int krow = t >> 1;
    const int kcb  = (t & 1) * 32;
    f16x8 kr0, kr1, kr2, kr3, vr0, vr1, vr2, vr3;
    {
        const f16* kp = Kg + krow * 64 + kcb;
        kr0 = *(const f16x8*)(kp + 0);
        kr1 = *(const f16x8*)(kp + 8);
        kr2 = *(const f16x8*)(kp + 16);
        kr3 = *(const f16x8*)(kp + 24);
        const f16* vp = Vg + (2 * lane) * 64 + w * 16;
        vr0 = *(const f16x8*)(vp + 0);
        vr1 = *(const f16x8*)(vp + 8);
        vr2 = *(const f16x8*)(vp + 64);
        vr3 = *(const f16x8*)(vp + 72);
    }

    __syncthreads();   // Q staged
    f16x8 qf0, qf1;
    {
        f16x4 l0 = *(const f16x4*)&QP[(w * 16 + sub) * PPIT + quad * 8];
        f16x4 l1 = *(const f16x4*)&QP[(w * 16 + sub) * PPIT + quad * 8 + 4];
        f16x4 l2 = *(const f16x4*)&QP[(w * 16 + sub) * PPIT + 32 + quad * 8];
        f16x4 l3 = *(const f16x4*)&QP[(w * 16 + sub) * PPIT + 32 + quad * 8 + 4];
        qf0 = (f16x8){l0[0], l0[1], l0[2], l0[3], l1[0], l1[1], l1[2], l1[3]};
        qf1 = (f16x8){l2[0], l2[1], l2[2], l2[3], l3[0], l3[1], l3[2], l3[3]};
    }

    // store chunk 0 into LDS
    {
        f16* kd = &Ks[krow * KP + kcb];
        *(f16x8*)(kd + 0)  = kr0;
        *(f16x8*)(kd + 8)  = kr1;
        *(f16x8*)(kd + 16) = kr2;
        *(f16x8*)(kd + 24) = kr3;
#pragma unroll
        for (int j = 0; j < 8; ++j) {
            *(f16x2*)&Vt[(w * 16 + j) * VP + 2 * lane]     = (f16x2){vr0[j], vr2[j]};
            *(f16x2*)&Vt[(w * 16 + 8 + j) * VP + 2 * lane] = (f16x2){vr1[j], vr3[j]};
        }
    }
    __syncthreads();

    const f16x8 ones = {(f16)1.f, (f16)1.f, (f16)1.f, (f16)1.f,
                        (f16)1.f, (f16)1.f, (f16)1.f, (f16)1.f};
    f32x4 o[4];
    f32x4 l_acc = (f32x4){0.f, 0.f, 0.f, 0.f};
    float m_run[4];
#pragma unroll
    for (int dt = 0; dt < 4; ++dt) o[dt] = (f32x4){0.f, 0.f, 0.f, 0.f};
#pragma unroll
    for (int r = 0; r < 4; ++r) m_run[r] = -1e30f;

    const int NITER = SEQ / 128;
    for (int c = 0; c < NITER; ++c) {
        const int c0 = c * 128;
        // prefetch next chunk (fully overlapped with compute below)
        if (c + 1 < NITER) {
            const f16* kp = Kg + (c0 + 128 + krow) * 64 + kcb;
            kr0 = *(const f16x8*)(kp + 0);
            kr1 = *(const f16x8*)(kp + 8);
            kr2 = *(const f16x8*)(kp + 16);
            kr3 = *(const f16x8*)(kp + 24);
            const f16* vp = Vg + (c0 + 128 + 2 * lane) * 64 + w * 16;
            vr0 = *(const f16x8*)(vp + 0);
            vr1 = *(const f16x8*)(vp + 8);
            vr2 = *(const f16x8*)(vp + 64);
            vr3 = *(const f16x8*)(vp + 72);
        }

        // S = Q.K^T over 128 keys (8 column tiles)
        f32x4 s[8];
#pragma unroll
        for (int ct = 0; ct < 8; ++ct) {
            f16x8 kf0 = *(const f16x8*)&Ks[(ct * 16 + sub) * KP + quad * 8];
            f16x8 kf1 = *(const f16x8*)&Ks[(ct * 16 + sub) * KP + 32 + quad * 8];
            f32x4 a = (f32x4){0.f, 0.f, 0.f, 0.f};
            a = __builtin_amdgcn_mfma_f32_16x16x32_f16(qf0, kf0, a, 0, 0, 0);
            a = __builtin_amdgcn_mfma_f32_16x16x32_f16(qf1, kf1, a, 0, 0, 0);
            s[ct] = a;
        }
        if (has_mask) {   // rare path: fp32 mask direct, scaled to log2 domain
#pragma unroll
            for (int ct = 0; ct < 8; ++ct)
#pragma unroll
                for (int r = 0; r < 4; ++r)
                    s[ct][r] += LOG2E * Mg[(size_t)r * SEQ + c0 + ct * 16 + sub];
        }
        // row max over 128 cols + running, packed-f16 16-lane butterfly
        float mnew[4];
#pragma unroll
        for (int r = 0; r < 4; ++r) {
            float a01 = fmaxf(s[0][r], s[1][r]), a23 = fmaxf(s[2][r], s[3][r]);
            float a45 = fmaxf(s[4][r], s[5][r]), a67 = fmaxf(s[6][r], s[7][r]);
            mnew[r] = fmaxf(fmaxf(fmaxf(a01, a23), fmaxf(a45, a67)), m_run[r]);
        }
        {
            union { f16x2 h; int i; } p0, p1, v0, v1;
            p0.h = (f16x2){(f16)mnew[0], (f16)mnew[1]};
            p1.h = (f16x2){(f16)mnew[2], (f16)mnew[3]};
#pragma unroll
            for (int mk = 1; mk < 16; mk <<= 1) {
                v0.i = __shfl_xor(p0.i, mk, 64);
                v1.i = __shfl_xor(p1.i, mk, 64);
                p0.h = __builtin_elementwise_max(p0.h, v0.h);
                p1.h = __builtin_elementwise_max(p1.h, v1.h);
            }
            mnew[0] = (float)p0.h[0]; mnew[1] = (float)p0.h[1];
            mnew[2] = (float)p1.h[0]; mnew[3] = (float)p1.h[1];
        }
        float alpha[4];
#pragma unroll
        for (int r = 0; r < 4; ++r) {
            alpha[r] = exp2f(m_run[r] - mnew[r]);
            m_run[r] = mnew[r];
        }
        // rescale O and l
#pragma unroll
        for (int dt = 0; dt < 4; ++dt)
#pragma unroll
            for (int r = 0; r < 4; ++r) o[dt][r] *= alpha[r];
#pragma unroll
        for (int r = 0; r < 4; ++r) l_acc[r] *= alpha[r];

        // two 64-key halves through the shared P tile (wave-private rows)
#pragma unroll
        for (int hf = 0; hf < 2; ++hf) {
#pragma unroll
            for (int ct = 0; ct < 4; ++ct)
#pragma unroll
                for (int r = 0; r < 4; ++r) {
                    float p = exp2f(s[hf * 4 + ct][r] - mnew[r]);
                    QP[(w * 16 + quad * 4 + r) * PPIT + ct * 16 + sub] = (f16)p;
                }
            f16x4 p00 = *(const f16x4*)&QP[(w * 16 + sub) * PPIT + quad * 8];
            f16x4 p01 = *(const f16x4*)&QP[(w * 16 + sub) * PPIT + quad * 8 + 4];
            f16x4 p10 = *(const f16x4*)&QP[(w * 16 + sub) * PPIT + 32 + quad * 8];
            f16x4 p11 = *(const f16x4*)&QP[(w * 16 + sub) * PPIT + 32 + quad * 8 + 4];
            f16x8 pf0 = {p00[0], p00[1], p00[2], p00[3], p01[0], p01[1], p01[2], p01[3]};
            f16x8 pf1 = {p10[0], p10[1], p10[2], p10[3], p11[0], p11[1], p11[2], p11[3]};
            l_acc = __builtin_amdgcn_mfma_f32_16x16x32_f16(pf0, ones, l_acc, 0, 0, 0);
            l_acc = __builtin_amdgcn_mfma_f32_16x16x32_f16(pf1, ones, l_acc, 0, 0, 0);
#pragma unroll
            for (int dt = 0; dt < 4; ++dt) {
                f16x8 vf0 = *(const f16x8*)&Vt[(dt * 16 + sub) * VP + hf * 64 + quad * 8];
                f16x8 vf1 = *(const f16x8*)&Vt[(dt * 16 + sub) * VP + hf * 64 + 32 + quad * 8];
                o[dt] = __builtin_amdgcn_mfma_f32_16x16x32_f16(pf0, vf0, o[dt], 0, 0, 0);
                o[dt] = __builtin_amdgcn_mfma_f32_16x16x32_f16(pf1, vf1, o[dt], 0, 0, 0);
            }
        }

        if (c + 1 < NITER) {   // restage K/V for next chunk
            __syncthreads();   // all reads of current chunk done
            f16* kd = &Ks[krow * KP + kcb];
            *(f16x8*)(kd + 0)  = kr0;
            *(f16x8*)(kd + 8)  = kr1;
            *(f16x8*)(kd + 16) = kr2;
            *(f16x8*)(kd + 24) = kr3;
#pragma unroll
            for (int j = 0; j < 8; ++j) {
                *(f16x2*)&Vt[(w * 16 + j) * VP + 2 * lane]     = (f16x2){vr0[j], vr2[j]};
                *(f16x2*)&Vt[(w * 16 + 8 + j) * VP + 2 * lane] = (f16x2){vr1[j], vr3[j]};
            }
            __syncthreads();
        }
    }
    // epilogue
    float lsc = lscale[h];
#pragma unroll
    for (int r = 0; r < 4; ++r) {
        float inv = lsc / l_acc[r];
        int q = qb + w * 16 + quad * 4 + r;
#pragma unroll
        for (int dt = 0; dt < 4; ++dt)
            Og[((size_t)n * SEQ + q) * CH + h * 64 + dt * 16 + sub] =
                (f16)(o[dt][r] * inv);
    }
}

// ---------------------------------------------------------------------------
// Output projection, 64x64 tile -> 768 blocks = exactly 3/CU (the old
// 128x128 tiling gave only 192 blocks: 64 CUs idle and no latency hiding).
// 4 waves; wave w computes rows m0..m0+63 x cols f0+w*16..+15. BK=64.
// ---------------------------------------------------------------------------
__global__ __launch_bounds__(256, 4) void out_gemm(const f16* __restrict__ A,
                                                   const f16* __restrict__ Wh,
                                                   const float* __restrict__ bias,
                                                   float* __restrict__ out)
{
    __shared__ f16 As[64 * GP2];
    __shared__ f16 Bs[64 * GP2];
    const int t    = threadIdx.x;
    const int w    = t >> 6;
    const int lane = t & 63;
    const int quad = lane >> 4;
    const int sub  = lane & 15;
    const int f0   = blockIdx.x * 64;
    const int m0   = blockIdx.y * 64;
    const int srow = t >> 2;            // 0..63
    const int sk   = (t & 3) * 16;      // 0,16,32,48

    const f16* ag = A + (size_t)(m0 + srow) * CH + sk;
    const f16* bg = Wh + (size_t)(f0 + srow) * CH + sk;
    f16x8 a0 = *(const f16x8*)(ag);
    f16x8 a1 = *(const f16x8*)(ag + 8);
    f16x8 b0 = *(const f16x8*)(bg);
    f16x8 b1 = *(const f16x8*)(bg + 8);

    f32x4 acc[4];
#pragma unroll
    for (int i = 0; i < 4; ++i) acc[i] = (f32x4){0.f, 0.f, 0.f, 0.f};

    for (int k0 = 0; k0 < CH; k0 += 64) {
        __syncthreads();
        *(f16x8*)&As[srow * GP2 + sk + 0] = a0;
        *(f16x8*)&As[srow * GP2 + sk + 8] = a1;
        *(f16x8*)&Bs[srow * GP2 + sk + 0] = b0;
        *(f16x8*)&Bs[srow * GP2 + sk + 8] = b1;
        __syncthreads();
        if (k0 + 64 < CH) {
            a0 = *(const f16x8*)(ag + k0 + 64);
            a1 = *(const f16x8*)(ag + k0 + 72);
            b0 = *(const f16x8*)(bg + k0 + 64);
            b1 = *(const f16x8*)(bg + k0 + 72);
        }
#pragma unroll
        for (int kk = 0; kk < 64; kk += 32) {
            f16x8 bf = *(const f16x8*)&Bs[(w * 16 + sub) * GP2 + kk + quad * 8];
#pragma unroll
            for (int i = 0; i < 4; ++i) {
                f16x8 af = *(const f16x8*)&As[(i * 16 + sub) * GP2 + kk + quad * 8];
                acc[i] = __builtin_amdgcn_mfma_f32_16x16x32_f16(af, bf, acc[i], 0, 0, 0);
            }
        }
    }
    float bb = bias[f0 + w * 16 + sub];
#pragma unroll
    for (int i = 0; i < 4; ++i)
#pragma unroll
        for (int r = 0; r < 4; ++r) {
            int m = m0 + i * 16 + quad * 4 + r;
            out[(size_t)m * CH + f0 + w * 16 + sub] = acc[i][r] + bb;
        }
}

extern "C" void kernel_launch(void* const* d_in, const int* in_sizes, int n_in,
                              void* d_out, int out_size, void* d_ws, size_t ws_size,
                              hipStream_t stream) {
    const float* x    = (const float*)d_in[0];
    const float* w1   = (const float*)d_in[1];
    const float* b1   = (const float*)d_in[2];
    const float* ls   = (const float*)d_in[3];
    const float* lrn  = (const float*)d_in[4];
    const float* w2   = (const float*)d_in[5];
    const float* b2   = (const float*)d_in[6];
    const float* msk  = (const float*)d_in[7];
    f16*   ws16 = (f16*)d_ws;
    int*   flag = (int*)(ws16 + FLAGO);
    float* out  = (float*)d_out;

    (void)hipMemsetAsync(flag, 0, 4, stream);
    hipLaunchKernelGGL(cvt_f16, dim3(4096, 4), dim3(256), 0, stream,
                       x, w1, w2, msk,
                       ws16 + XHOFF, ws16 + W1OFF, ws16 + W2OFF, flag);
    hipLaunchKernelGGL(qkv_gemm, dim3(F3 / 128, (NB * SEQ) / 128), dim3(256), 0, stream,
                       ws16 + XHOFF, ws16 + W1OFF, b1, ls, ws16);
    hipLaunchKernelGGL(attn, dim3(SEQ / 64, NH, NB), dim3(256), 0, stream,
                       ws16, ws16 + QSZ, ws16 + 2 * QSZ, msk, lrn, flag,
                       ws16 + OATT);
    hipLaunchKernelGGL(out_gemm, dim3(CH / 64, (NB * SEQ) / 64), dim3(256), 0, stream,
                       ws16 + OATT, ws16 + W2OFF, b2, out);
}

// Round 13
// 207.724 us; speedup vs baseline: 1.3256x; 1.0091x over previous
//
#include <hip/hip_runtime.h>
#include <math.h>

// Problem constants
#define NB   2
#define SEQ  2048
#define CH   768
#define NH   12
#define HD   64
#define F3   2304
#define LSMAX 4.605170185988092f
#define LOG2E 1.4426950408889634f

typedef _Float16 f16;
typedef __attribute__((ext_vector_type(8))) _Float16 f16x8;
typedef __attribute__((ext_vector_type(4))) _Float16 f16x4;
typedef __attribute__((ext_vector_type(2))) _Float16 f16x2;
typedef __attribute__((ext_vector_type(4))) float f32x4;

typedef __attribute__((address_space(3))) void lds_void;
typedef __attribute__((address_space(1))) const void gbl_cvoid;

// f16 workspace layout (units: f16 elements)
#define QSZ   3145728                 // per Q/K/V tensor
#define OATT  (3 * QSZ)               // attn out [N,L,C] f16 (3145728)
#define XHOFF 12582912                // x -> f16 (3145728)
#define W1OFF 15728640                // in_proj_w -> f16 (1769472)
#define W2OFF 17498112                // out_proj_w -> f16 (589824)
#define FLAGO 18087936                // int flag: mask nonzero

// LDS pitches
#define KP   72    // attn K tile: 144B rows, 16B-aligned b128
#define VP   136   // attn Vt tile (128 keys): 272B rows, 16B-aligned b128
#define PPIT 76    // attn Q/P tile: 152B rows, b64 frag reads
#define GP2  72    // out GEMM BK=64 tile: 144B rows, 16B-aligned b128

// ---------------------------------------------------------------------------
// fp32 -> f16 convert of X, W1, W2 (one-time; GEMMs re-read these many times,
// so converting once beats fused conversion — measured R10). Mask: flag scan.
// ---------------------------------------------------------------------------
__global__ __launch_bounds__(256) void cvt_f16(const float* __restrict__ X,
                                               const float* __restrict__ W1,
                                               const float* __restrict__ W2,
                                               const float* __restrict__ M,
                                               f16* __restrict__ Xh,
                                               f16* __restrict__ W1h,
                                               f16* __restrict__ W2h,
                                               int* __restrict__ flag)
{
    int tid = blockIdx.x * 256 + threadIdx.x;
    if (blockIdx.y == 3) {   // mask: flag-only scan
        if (tid < 1048576) {
            float4 v = ((const float4*)M)[tid];
            bool nz = (v.x != 0.f) || (v.y != 0.f) || (v.z != 0.f) || (v.w != 0.f);
            if (__any(nz) && (threadIdx.x & 63) == 0) atomicOr(flag, 1);
        }
        return;
    }
    const float* src; f16* dst; int n4;
    switch (blockIdx.y) {
        case 0:  src = X;  dst = Xh;  n4 = 786432;  break;
        case 1:  src = W1; dst = W1h; n4 = 442368;  break;
        default: src = W2; dst = W2h; n4 = 147456;  break;
    }
    if (tid < n4) {
        float4 v = ((const float4*)src)[tid];
        f16x4 o = {(f16)v.x, (f16)v.y, (f16)v.z, (f16)v.w};
        ((f16x4*)dst)[tid] = o;
    }
}

// ---------------------------------------------------------------------------
// QKV GEMM with async global->LDS staging (global_load_lds width=16):
// unpadded 128x32-f16 tiles, 16B chunks XOR-swizzled (slot = row*4 +
// (cb ^ (row&3))) so the LDS side is wave-uniform-base + lane*16 while
// b128 frag reads stay at the uniform bank floor. Double-buffered: loads
// for tile k+1 issue after the barrier and drain at the next barrier.
// 128x128 tile, 4 waves 2x2, BK=32. Epilogue: bias, l2-norm Q/K rows,
// fold exp(min(ls,MAX))*LOG2E into Q.
// ---------------------------------------------------------------------------
__global__ __launch_bounds__(256, 4) void qkv_gemm(const f16* __restrict__ Xh,
                                                   const f16* __restrict__ Wh,
                                                   const float* __restrict__ bias,
                                                   const float* __restrict__ logit_scale,
                                                   f16* __restrict__ qkv16)
{
    __shared__ f16 As[2][128 * 32];   // 8 KB per buffer, swizzled
    __shared__ f16 Bs[2][128 * 32];
    const int t    = threadIdx.x;
    const int w    = t >> 6;
    const int lane = t & 63;
    const int quad = lane >> 4;
    const int sub  = lane & 15;
    const int wm   = w & 1, wn = w >> 1;
    const int f0   = blockIdx.x * 128;
    const int m0   = blockIdx.y * 128;

    // staging slots: this thread owns 16B slots s0 = t and s1 = 256 + t
    const int s0 = t, s1 = 256 + t;
    const int r0 = s0 >> 2, cb0 = ((s0 & 3) ^ (r0 & 3)) * 8;
    const int r1 = s1 >> 2, cb1 = ((s1 & 3) ^ (r1 & 3)) * 8;
    const f16* ga0 = Xh + (size_t)(m0 + r0) * CH + cb0;
    const f16* ga1 = Xh + (size_t)(m0 + r1) * CH + cb1;
    const f16* gb0 = Wh + (size_t)(f0 + r0) * CH + cb0;
    const f16* gb1 = Wh + (size_t)(f0 + r1) * CH + cb1;

    f32x4 acc[4][4];
#pragma unroll
    for (int i = 0; i < 4; ++i)
#pragma unroll
        for (int j = 0; j < 4; ++j) acc[i][j] = (f32x4){0.f, 0.f, 0.f, 0.f};

    // frag-read byte chunks (swizzle: p = quad ^ (row&3), row&3 == sub&3)
    const int pch = (quad ^ (sub & 3)) * 8;   // f16 offset of 16B chunk

    // prime buffer 0
    __builtin_amdgcn_global_load_lds((gbl_cvoid*)(ga0), (lds_void*)&As[0][s0 * 8], 16, 0, 0);
    __builtin_amdgcn_global_load_lds((gbl_cvoid*)(ga1), (lds_void*)&As[0][s1 * 8], 16, 0, 0);
    __builtin_amdgcn_global_load_lds((gbl_cvoid*)(gb0), (lds_void*)&Bs[0][s0 * 8], 16, 0, 0);
    __builtin_amdgcn_global_load_lds((gbl_cvoid*)(gb1), (lds_void*)&Bs[0][s1 * 8], 16, 0, 0);
    __syncthreads();   // drain: buf0 ready

    for (int k0 = 0; k0 < CH; k0 += 32) {
        const int cur = (k0 >> 5) & 1, nxt = cur ^ 1;
        if (k0 + 32 < CH) {   // issue loads for next tile into the other buffer
            __builtin_amdgcn_global_load_lds((gbl_cvoid*)(ga0 + k0 + 32), (lds_void*)&As[nxt][s0 * 8], 16, 0, 0);
            __builtin_amdgcn_global_load_lds((gbl_cvoid*)(ga1 + k0 + 32), (lds_void*)&As[nxt][s1 * 8], 16, 0, 0);
            __builtin_amdgcn_global_load_lds((gbl_cvoid*)(gb0 + k0 + 32), (lds_void*)&Bs[nxt][s0 * 8], 16, 0, 0);
            __builtin_amdgcn_global_load_lds((gbl_cvoid*)(gb1 + k0 + 32), (lds_void*)&Bs[nxt][s1 * 8], 16, 0, 0);
        }
        f16x8 af[4], bf[4];
#pragma unroll
        for (int i = 0; i < 4; ++i) {
            af[i] = *(const f16x8*)&As[cur][(wm * 64 + i * 16 + sub) * 32 + pch];
            bf[i] = *(const f16x8*)&Bs[cur][(wn * 64 + i * 16 + sub) * 32 + pch];
        }
#pragma unroll
        for (int i = 0; i < 4; ++i)
#pragma unroll
            for (int j = 0; j < 4; ++j)
                acc[i][j] = __builtin_amdgcn_mfma_f32_16x16x32_f16(af[i], bf[j], acc[i][j], 0, 0, 0);
        __syncthreads();   // drain next-tile loads; readers done with cur
    }

    const int t3 = f0 / CH;                       // 0=q,1=k,2=v (block-uniform)
    const int h  = ((f0 + wn * 64) % CH) >> 6;    // wave-uniform head
    f16* dst = qkv16 + (size_t)t3 * QSZ;
    float lsv = (t3 == 0) ? __expf(fminf(logit_scale[h], LSMAX)) * LOG2E : 1.0f;
    float bb[4];
#pragma unroll
    for (int j = 0; j < 4; ++j) bb[j] = bias[f0 + wn * 64 + j * 16 + sub];
#pragma unroll
    for (int i = 0; i < 4; ++i) {
#pragma unroll
        for (int r = 0; r < 4; ++r) {
            int m = m0 + wm * 64 + i * 16 + quad * 4 + r;
            int n = m >> 11, l = m & 2047;
            float v[4];
#pragma unroll
            for (int j = 0; j < 4; ++j) v[j] = acc[i][j][r] + bb[j];
            float scale = 1.0f;
            if (t3 < 2) {
                float ss = v[0] * v[0] + v[1] * v[1] + v[2] * v[2] + v[3] * v[3];
#pragma unroll
                for (int mk = 1; mk < 16; mk <<= 1) ss += __shfl_xor(ss, mk, 64);
                scale = 1.0f / fmaxf(sqrtf(ss), 1e-12f);
                if (t3 == 0) scale *= lsv;
            }
            f16* drow = dst + (((size_t)n * NH + h) * SEQ + l) * HD;
#pragma unroll
            for (int j = 0; j < 4; ++j)
                drow[j * 16 + sub] = (f16)(v[j] * scale);
        }
    }
}

// ---------------------------------------------------------------------------
// Flash attention (R7 winner, verbatim): f16 MFMA, KC=128 keys/iteration,
// log2-domain softmax, single-buffer K/V LDS + full register prefetch,
// P in two 64-key halves through one shared Q/P tile, l via ones-MFMA.
// ---------------------------------------------------------------------------
__global__ __launch_bounds__(256, 3) void attn(const f16* __restrict__ Qh,
                                               const f16* __restrict__ Kh,
                                               const f16* __restrict__ Vh,
                                               const float* __restrict__ M32,
                                               const float* __restrict__ lscale,
                                               const int* __restrict__ flag,
                                               f16* __restrict__ Og)
{
    __shared__ f16 Ks[128 * KP];    // [key][d]          18.4 KB
    __shared__ f16 Vt[64 * VP];     // [d][key 0..127]   17.4 KB
    __shared__ f16 QP[64 * PPIT];   // Q tile -> P tile   9.7 KB

    const int t    = threadIdx.x;
    const int w    = t >> 6;
    const int lane = t & 63;
    const int quad = lane >> 4;
    const int sub  = lane & 15;
    const int qb   = blockIdx.x * 64;
    const int h    = blockIdx.y, n = blockIdx.z;
    const bool has_mask = (*flag) != 0;

    const f16* Qg = Qh + ((size_t)(n * NH + h) * SEQ + qb) * HD;
    const f16* Kg = Kh + (size_t)(n * NH + h) * SEQ * HD;
    const f16* Vg = Vh + (size_t)(n * NH + h) * SEQ * HD;
    const float* Mg = M32 + (size_t)(qb + w * 16 + quad * 4) * SEQ;

    // stage Q
#pragma unroll
    for (int rep = 0; rep < 2; ++rep) {
        int id = rep * 256 + t;
        int row = id >> 3, c8 = id & 7;
        f16x8 v = *(const f16x8*)&Qg[row * 64 + c8 * 8];
        *(f16x4*)&QP[row * PPIT + c8 * 8 + 0] = (f16x4){v[0], v[1], v[2], v[3]};
        *(f16x4*)&QP[row * PPIT + c8 * 8 + 4] = (f16x4){v[4], v[5], v[6], v[7]};
    }

    // prefetch chunk 0: K 4 b128 (row t>>1, colblock (t&1)*32),
    //                   V 4 b128 (keys 2*lane, 2*lane+1; d-slice w*16..+16)
    const int krow = t >> 1;
    const int kcb  = (t & 1) * 32;
    f16x8 kr0, kr1, kr2, kr3, vr0, vr1, vr2, vr3;
    {
        const f16* kp = Kg + krow * 64 + kcb;
        kr0 = *(const f16x8*)(kp + 0);
        kr1 = *(const f16x8*)(kp + 8);
        kr2 = *(const f16x8*)(kp + 16);
        kr3 = *(const f16x8*)(kp + 24);
        const f16* vp = Vg + (2 * lane) * 64 + w * 16;
        vr0 = *(const f16x8*)(vp + 0);
        vr1 = *(const f16x8*)(vp + 8);
        vr2 = *(const f16x8*)(vp + 64);
        vr3 = *(const f16x8*)(vp + 72);
    }

    __syncthreads();   // Q staged
    f16x8 qf0, qf1;
    {
        f16x4 l0 = *(const f16x4*)&QP[(w * 16 + sub) * PPIT + quad * 8];
        f16x4 l1 = *(const f16x4*)&QP[(w * 16 + sub) * PPIT + quad * 8 + 4];
        f16x4 l2 = *(const f16x4*)&QP[(w * 16 + sub) * PPIT + 32 + quad * 8];
        f16x4 l3 = *(const f16x4*)&QP[(w * 16 + sub) * PPIT + 32 + quad * 8 + 4];
        qf0 = (f16x8){l0[0], l0[1], l0[2], l0[3], l1[0], l1[1], l1[2], l1[3]};
        qf1 = (f16x8){l2[0], l2[1], l2[2], l2[3], l3[0], l3[1], l3[2], l3[3]};
    }

    // store chunk 0 into LDS
    {
        f16* kd = &Ks[krow * KP + kcb];
        *(f16x8*)(kd + 0)  = kr0;
        *(f16x8*)(kd + 8)  = kr1;
        *(f16x8*)(kd + 16) = kr2;
        *(f16x8*)(kd + 24) = kr3;
#pragma unroll
        for (int j = 0; j < 8; ++j) {
            *(f16x2*)&Vt[(w * 16 + j) * VP + 2 * lane]     = (f16x2){vr0[j], vr2[j]};
            *(f16x2*)&Vt[(w * 16 + 8 + j) * VP + 2 * lane] = (f16x2){vr1[j], vr3[j]};
        }
    }
    __syncthreads();

    const f16x8 ones = {(f16)1.f, (f16)1.f, (f16)1.f, (f16)1.f,
                        (f16)1.f, (f16)1.f, (f16)1.f, (f16)1.f};
    f32x4 o[4];
    f32x4 l_acc = (f32x4){0.f, 0.f, 0.f, 0.f};
    float m_run[4];
#pragma unroll
    for (int dt = 0; dt < 4; ++dt) o[dt] = (f32x4){0.f, 0.f, 0.f, 0.f};
#pragma unroll
    for (int r = 0; r < 4; ++r) m_run[r] = -1e30f;

    const int NITER = SEQ / 128;
    for (int c = 0; c < NITER; ++c) {
        const int c0 = c * 128;
        // prefetch next chunk (fully overlapped with compute below)
        if (c + 1 < NITER) {
            const f16* kp = Kg + (c0 + 128 + krow) * 64 + kcb;
            kr0 = *(const f16x8*)(kp + 0);
            kr1 = *(const f16x8*)(kp + 8);
            kr2 = *(const f16x8*)(kp + 16);
            kr3 = *(const f16x8*)(kp + 24);
            const f16* vp = Vg + (c0 + 128 + 2 * lane) * 64 + w * 16;
            vr0 = *(const f16x8*)(vp + 0);
            vr1 = *(const f16x8*)(vp + 8);
            vr2 = *(const f16x8*)(vp + 64);
            vr3 = *(const f16x8*)(vp + 72);
        }

        // S = Q.K^T over 128 keys (8 column tiles)
        f32x4 s[8];
#pragma unroll
        for (int ct = 0; ct < 8; ++ct) {
            f16x8 kf0 = *(const f16x8*)&Ks[(ct * 16 + sub) * KP + quad * 8];
            f16x8 kf1 = *(const f16x8*)&Ks[(ct * 16 + sub) * KP + 32 + quad * 8];
            f32x4 a = (f32x4){0.f, 0.f, 0.f, 0.f};
            a = __builtin_amdgcn_mfma_f32_16x16x32_f16(qf0, kf0, a, 0, 0, 0);
            a = __builtin_amdgcn_mfma_f32_16x16x32_f16(qf1, kf1, a, 0, 0, 0);
            s[ct] = a;
        }
        if (has_mask) {   // rare path: fp32 mask direct, scaled to log2 domain
#pragma unroll
            for (int ct = 0; ct < 8; ++ct)
#pragma unroll
                for (int r = 0; r < 4; ++r)
                    s[ct][r] += LOG2E * Mg[(size_t)r * SEQ + c0 + ct * 16 + sub];
        }
        // row max over 128 cols + running, packed-f16 16-lane butterfly
        float mnew[4];
#pragma unroll
        for (int r = 0; r < 4; ++r) {
            float a01 = fmaxf(s[0][r], s[1][r]), a23 = fmaxf(s[2][r], s[3][r]);
            float a45 = fmaxf(s[4][r], s[5][r]), a67 = fmaxf(s[6][r], s[7][r]);
            mnew[r] = fmaxf(fmaxf(fmaxf(a01, a23), fmaxf(a45, a67)), m_run[r]);
        }
        {
            union { f16x2 h; int i; } p0, p1, v0, v1;
            p0.h = (f16x2){(f16)mnew[0], (f16)mnew[1]};
            p1.h = (f16x2){(f16)mnew[2], (f16)mnew[3]};
#pragma unroll
            for (int mk = 1; mk < 16; mk <<= 1) {
                v0.i = __shfl_xor(p0.i, mk, 64);
                v1.i = __shfl_xor(p1.i, mk, 64);
                p0.h = __builtin_elementwise_max(p0.h, v0.h);
                p1.h = __builtin_elementwise_max(p1.h, v1.h);
            }
            mnew[0] = (float)p0.h[0]; mnew[1] = (float)p0.h[1];
            mnew[2] = (float)p1.h[0]; mnew[3] = (float)p1.h[1];
        }
        float alpha[4];
#pragma unroll
        for (int r = 0; r < 4; ++r) {
            alpha[r] = exp2f(m_run[r] - mnew[r]);
            m_run[r] = mnew[r];
        }
        // rescale O and l
#pragma unroll
        for (int dt = 0; dt < 4; ++dt)
#pragma unroll
            for (int r = 0; r < 4; ++r) o[dt][r] *= alpha[r];
#pragma unroll
        for (int r = 0; r < 4; ++r) l_acc[r] *= alpha[r];

        // two 64-key halves through the shared P tile (wave-private rows)
#pragma unroll
        for (int hf = 0; hf < 2; ++hf) {
#pragma unroll
            for (int ct = 0; ct < 4; ++ct)
#pragma unroll
                for (int r = 0; r < 4; ++r) {
                    float p = exp2f(s[hf * 4 + ct][r] - mnew[r]);
                    QP[(w * 16 + quad * 4 + r) * PPIT + ct * 16 + sub] = (f16)p;
                }
            f16x4 p00 = *(const f16x4*)&QP[(w * 16 + sub) * PPIT + quad * 8];
            f16x4 p01 = *(const f16x4*)&QP[(w * 16 + sub) * PPIT + quad * 8 + 4];
            f16x4 p10 = *(const f16x4*)&QP[(w * 16 + sub) * PPIT + 32 + quad * 8];
            f16x4 p11 = *(const f16x4*)&QP[(w * 16 + sub) * PPIT + 32 + quad * 8 + 4];
            f16x8 pf0 = {p00[0], p00[1], p00[2], p00[3], p01[0], p01[1], p01[2], p01[3]};
            f16x8 pf1 = {p10[0], p10[1], p10[2], p10[3], p11[0], p11[1], p11[2], p11[3]};
            l_acc = __builtin_amdgcn_mfma_f32_16x16x32_f16(pf0, ones, l_acc, 0, 0, 0);
            l_acc = __builtin_amdgcn_mfma_f32_16x16x32_f16(pf1, ones, l_acc, 0, 0, 0);
#pragma unroll
            for (int dt = 0; dt < 4; ++dt) {
                f16x8 vf0 = *(const f16x8*)&Vt[(dt * 16 + sub) * VP + hf * 64 + quad * 8];
                f16x8 vf1 = *(const f16x8*)&Vt[(dt * 16 + sub) * VP + hf * 64 + 32 + quad * 8];
                o[dt] = __builtin_amdgcn_mfma_f32_16x16x32_f16(pf0, vf0, o[dt], 0, 0, 0);
                o[dt] = __builtin_amdgcn_mfma_f32_16x16x32_f16(pf1, vf1, o[dt], 0, 0, 0);
            }
        }

        if (c + 1 < NITER) {   // restage K/V for next chunk
            __syncthreads();   // all reads of current chunk done
            f16* kd = &Ks[krow * KP + kcb];
            *(f16x8*)(kd + 0)  = kr0;
            *(f16x8*)(kd + 8)  = kr1;
            *(f16x8*)(kd + 16) = kr2;
            *(f16x8*)(kd + 24) = kr3;
#pragma unroll
            for (int j = 0; j < 8; ++j) {
                *(f16x2*)&Vt[(w * 16 + j) * VP + 2 * lane]     = (f16x2){vr0[j], vr2[j]};
                *(f16x2*)&Vt[(w * 16 + 8 + j) * VP + 2 * lane] = (f16x2){vr1[j], vr3[j]};
            }
            __syncthreads();
        }
    }
    // epilogue
    float lsc = lscale[h];
#pragma unroll
    for (int r = 0; r < 4; ++r) {
        float inv = lsc / l_acc[r];
        int q = qb + w * 16 + quad * 4 + r;
#pragma unroll
        for (int dt = 0; dt < 4; ++dt)
            Og[((size_t)n * SEQ + q) * CH + h * 64 + dt * 16 + sub] =
                (f16)(o[dt][r] * inv);
    }
}

// ---------------------------------------------------------------------------
// Output projection, 64x64 tile -> 768 blocks = exactly 3/CU. 4 waves;
// wave w computes rows m0..m0+63 x cols f0+w*16..+15. BK=64.
// ---------------------------------------------------------------------------
__global__ __launch_bounds__(256, 4) void out_gemm(const f16* __restrict__ A,
                                                   const f16* __restrict__ Wh,
                                                   const float* __restrict__ bias,
                                                   float* __restrict__ out)
{
    __shared__ f16 As[64 * GP2];
    __shared__ f16 Bs[64 * GP2];
    const int t    = threadIdx.x;
    const int w    = t >> 6;
    const int lane = t & 63;
    const int quad = lane >> 4;
    const int sub  = lane & 15;
    const int f0   = blockIdx.x * 64;
    const int m0   = blockIdx.y * 64;
    const int srow = t >> 2;            // 0..63
    const int sk   = (t & 3) * 16;      // 0,16,32,48

    const f16* ag = A + (size_t)(m0 + srow) * CH + sk;
    const f16* bg = Wh + (size_t)(f0 + srow) * CH + sk;
    f16x8 a0 = *(const f16x8*)(ag);
    f16x8 a1 = *(const f16x8*)(ag + 8);
    f16x8 b0 = *(const f16x8*)(bg);
    f16x8 b1 = *(const f16x8*)(bg + 8);

    f32x4 acc[4];
#pragma unroll
    for (int i = 0; i < 4; ++i) acc[i] = (f32x4){0.f, 0.f, 0.f, 0.f};

    for (int k0 = 0; k0 < CH; k0 += 64) {
        __syncthreads();
        *(f16x8*)&As[srow * GP2 + sk + 0] = a0;
        *(f16x8*)&As[srow * GP2 + sk + 8] = a1;
        *(f16x8*)&Bs[srow * GP2 + sk + 0] = b0;
        *(f16x8*)&Bs[srow * GP2 + sk + 8] = b1;
        __syncthreads();
        if (k0 + 64 < CH) {
            a0 = *(const f16x8*)(ag + k0 + 64);
            a1 = *(const f16x8*)(ag + k0 + 72);
            b0 = *(const f16x8*)(bg + k0 + 64);
            b1 = *(const f16x8*)(bg + k0 + 72);
        }
#pragma unroll
        for (int kk = 0; kk < 64; kk += 32) {
            f16x8 bf = *(const f16x8*)&Bs[(w * 16 + sub) * GP2 + kk + quad * 8];
#pragma unroll
            for (int i = 0; i < 4; ++i) {
                f16x8 af = *(const f16x8*)&As[(i * 16 + sub) * GP2 + kk + quad * 8];
                acc[i] = __builtin_amdgcn_mfma_f32_16x16x32_f16(af, bf, acc[i], 0, 0, 0);
            }
        }
    }
    float bb = bias[f0 + w * 16 + sub];
#pragma unroll
    for (int i = 0; i < 4; ++i)
#pragma unroll
        for (int r = 0; r < 4; ++r) {
            int m = m0 + i * 16 + quad * 4 + r;
            out[(size_t)m * CH + f0 + w * 16 + sub] = acc[i][r] + bb;
        }
}

extern "C" void kernel_launch(void* const* d_in, const int* in_sizes, int n_in,
                              void* d_out, int out_size, void* d_ws, size_t ws_size,
                              hipStream_t stream) {
    const float* x    = (const float*)d_in[0];
    const float* w1   = (const float*)d_in[1];
    const float* b1   = (const float*)d_in[2];
    const float* ls   = (const float*)d_in[3];
    const float* lrn  = (const float*)d_in[4];
    const float* w2   = (const float*)d_in[5];
    const float* b2   = (const float*)d_in[6];
    const float* msk  = (const float*)d_in[7];
    f16*   ws16 = (f16*)d_ws;
    int*   flag = (int*)(ws16 + FLAGO);
    float* out  = (float*)d_out;

    (void)hipMemsetAsync(flag, 0, 4, stream);
    hipLaunchKernelGGL(cvt_f16, dim3(4096, 4), dim3(256), 0, stream,
                       x, w1, w2, msk,
                       ws16 + XHOFF, ws16 + W1OFF, ws16 + W2OFF, flag);
    hipLaunchKernelGGL(qkv_gemm, dim3(F3 / 128, (NB * SEQ) / 128), dim3(256), 0, stream,
                       ws16 + XHOFF, ws16 + W1OFF, b1, ls, ws16);
    hipLaunchKernelGGL(attn, dim3(SEQ / 64, NH, NB), dim3(256), 0, stream,
                       ws16, ws16 + QSZ, ws16 + 2 * QSZ, msk, lrn, flag,
                       ws16 + OATT);
    hipLaunchKernelGGL(out_gemm, dim3(CH / 64, (NB * SEQ) / 64), dim3(256), 0, stream,
                       ws16 + OATT, ws16 + W2OFF, b2, out);
}